// Round 2
// baseline (293.706 us; speedup 1.0000x reference)
//
#include <hip/hip_runtime.h>
#include <hip/hip_bf16.h>

// L=256, B=32, H=8, d_head=64, m=256, feature dim 2m=512, D_MODEL=512
#define L_SEQ 256
#define B_SZ  32
#define NH    8
#define DH    64
#define DM    512
#define FD    512
#define PM    256
#define ROWS  8192
#define QKVN  2048

typedef __bf16 bf16x8 __attribute__((ext_vector_type(8)));
typedef float f32x4 __attribute__((ext_vector_type(4)));
#define MFMA16(a, b, c) __builtin_amdgcn_mfma_f32_16x16x32_bf16((a), (b), (c), 0, 0, 0)

static __device__ __forceinline__ void stmix(void* p, long i, float v, int f32) {
  if (f32) ((float*)p)[i] = v;
  else     ((__bf16*)p)[i] = (__bf16)v;
}

// ---------------------------------------------------------------------------
// P0: prep — probe + h-cvt + 3 transposes + tiny cvts in one launch
// (validated rounds 7-8). Every block re-derives the dtype flag inline.
// ---------------------------------------------------------------------------
#define PREP_HB   2048
#define PREP_WT   256
#define PREP_WOT  64
#define PREP_PJ   4
#define PREP_TINY 1
#define PREP_BLOCKS (PREP_HB + PREP_WT + PREP_WOT + PREP_PJ + PREP_TINY)

__global__ __launch_bounds__(256) void prep(
    const void* __restrict__ h, const void* __restrict__ wqkv,
    const void* __restrict__ wo, const void* __restrict__ proj,
    const void* __restrict__ pi0, const void* __restrict__ pi1,
    const void* __restrict__ gam, const void* __restrict__ bet,
    int* __restrict__ flag, __bf16* __restrict__ hb, __bf16* __restrict__ wt,
    __bf16* __restrict__ wot, __bf16* __restrict__ projT,
    __bf16* __restrict__ pi0b, __bf16* __restrict__ pi1b,
    __bf16* __restrict__ gamb, __bf16* __restrict__ betb) {
  __shared__ float T[64][69];
  __shared__ int red[256];
  const int tid = threadIdx.x;
  int cnt = 0;
  {
    const unsigned short* hbits = (const unsigned short*)h;
    for (int i = 0; i < 16; ++i) {
      const unsigned short u = hbits[tid * 16 + i];
      if (((u >> 7) & 0xFF) >= 0xA0) ++cnt;
    }
  }
  red[tid] = cnt; __syncthreads();
  for (int s = 128; s > 0; s >>= 1) { if (tid < s) red[tid] += red[tid + s]; __syncthreads(); }
  const int f32 = (red[0] >= 64) ? 1 : 0;
  __syncthreads();

  const int blk = blockIdx.x;
  if (blk < PREP_HB) {
    const int i = blk * 256 + tid;
    if (f32) {
      const f32x4* s = (const f32x4*)h;
      const f32x4 a = s[i * 2], b = s[i * 2 + 1];
      bf16x8 t;
      t[0] = (__bf16)a[0]; t[1] = (__bf16)a[1]; t[2] = (__bf16)a[2]; t[3] = (__bf16)a[3];
      t[4] = (__bf16)b[0]; t[5] = (__bf16)b[1]; t[6] = (__bf16)b[2]; t[7] = (__bf16)b[3];
      *reinterpret_cast<bf16x8*>(hb + (long)i * 8) = t;
    } else {
      *reinterpret_cast<bf16x8*>(hb + (long)i * 8) = ((const bf16x8*)h)[i];
    }
    return;
  }
  const void* src; __bf16* dst; int M, N, n0, m0;
  if (blk < PREP_HB + PREP_WT) {
    const int x = blk - PREP_HB;
    src = wqkv; dst = wt; M = 512; N = 2048; n0 = (x & 31) * 64; m0 = (x >> 5) * 64;
  } else if (blk < PREP_HB + PREP_WT + PREP_WOT) {
    const int x = blk - PREP_HB - PREP_WT;
    src = wo; dst = wot; M = 512; N = 512; n0 = (x & 7) * 64; m0 = (x >> 3) * 64;
  } else if (blk < PREP_HB + PREP_WT + PREP_WOT + PREP_PJ) {
    const int x = blk - PREP_HB - PREP_WT - PREP_WOT;
    src = proj; dst = projT; M = 64; N = 256; n0 = x * 64; m0 = 0;
  } else {
    if (tid == 0) flag[0] = f32;
    if (f32) {
      const float* s0 = (const float*)pi0; const float* s1 = (const float*)pi1;
      const float* s2 = (const float*)gam; const float* s3 = (const float*)bet;
      for (int i = tid; i < NH * 256; i += 256) { pi0b[i] = (__bf16)s0[i]; pi1b[i] = (__bf16)s1[i]; }
      for (int i = tid; i < DM; i += 256)      { gamb[i] = (__bf16)s2[i]; betb[i] = (__bf16)s3[i]; }
    } else {
      const __bf16* s0 = (const __bf16*)pi0; const __bf16* s1 = (const __bf16*)pi1;
      const __bf16* s2 = (const __bf16*)gam; const __bf16* s3 = (const __bf16*)bet;
      for (int i = tid; i < NH * 256; i += 256) { pi0b[i] = s0[i]; pi1b[i] = s1[i]; }
      for (int i = tid; i < DM; i += 256)      { gamb[i] = s2[i]; betb[i] = s3[i]; }
    }
    return;
  }
  if (f32) {
    const float* s = (const float*)src;
#pragma unroll
    for (int rep = 0; rep < 16; ++rep) {
      const int i = rep * 4 + (tid >> 6), j = tid & 63;
      T[i][j] = s[(long)(m0 + i) * N + n0 + j];
    }
  } else {
    const __bf16* s = (const __bf16*)src;
#pragma unroll
    for (int rep = 0; rep < 16; ++rep) {
      const int i = rep * 4 + (tid >> 6), j = tid & 63;
      T[i][j] = (float)s[(long)(m0 + i) * N + n0 + j];
    }
  }
  __syncthreads();
#pragma unroll
  for (int rep = 0; rep < 16; ++rep) {
    const int i = rep * 4 + (tid >> 6), j = tid & 63;
    dst[(long)(n0 + i) * M + m0 + j] = (__bf16)T[j][i];
  }
}

// ---------------------------------------------------------------------------
// K1: qkv = hb @ w_qkv via MFMA with register prefetch (validated rounds 7-8).
// ---------------------------------------------------------------------------
__global__ __launch_bounds__(256) void gemm_h_wqkv(const __bf16* __restrict__ A,
                                                   const __bf16* __restrict__ Bt,
                                                   __bf16* __restrict__ C) {
  __shared__ __bf16 At[64][136];
  __shared__ __bf16 Bts[64][136];
  const int n0 = blockIdx.x * 64, m0 = blockIdx.y * 64;
  const int tid = threadIdx.x, lane = tid & 63, wv = tid >> 6;
  const int m = lane & 15, q = lane >> 4;
  const int r = tid >> 2, c0 = (tid & 3) * 32;
  const __bf16* ap = A + (long)(m0 + r) * DM + c0;
  const __bf16* bp = Bt + (long)(n0 + r) * DM + c0;
  f32x4 acc[4];
#pragma unroll
  for (int i = 0; i < 4; ++i) acc[i] = f32x4{0.f, 0.f, 0.f, 0.f};

  bf16x8 ar[4], br[4];
#pragma unroll
  for (int j = 0; j < 4; ++j) {
    ar[j] = *reinterpret_cast<const bf16x8*>(ap + j * 8);
    br[j] = *reinterpret_cast<const bf16x8*>(bp + j * 8);
  }
  for (int k0 = 0; k0 < DM; k0 += 128) {
    __syncthreads();
#pragma unroll
    for (int j = 0; j < 4; ++j) {
      *reinterpret_cast<bf16x8*>(&At[r][c0 + j * 8]) = ar[j];
      *reinterpret_cast<bf16x8*>(&Bts[r][c0 + j * 8]) = br[j];
    }
    if (k0 + 128 < DM) {
#pragma unroll
      for (int j = 0; j < 4; ++j) {
        ar[j] = *reinterpret_cast<const bf16x8*>(ap + k0 + 128 + j * 8);
        br[j] = *reinterpret_cast<const bf16x8*>(bp + k0 + 128 + j * 8);
      }
    }
    __syncthreads();
#pragma unroll
    for (int kk = 0; kk < 4; ++kk) {
      const bf16x8 af = *reinterpret_cast<const bf16x8*>(&At[wv * 16 + m][kk * 32 + q * 8]);
#pragma unroll
      for (int c = 0; c < 4; ++c) {
        const bf16x8 bf = *reinterpret_cast<const bf16x8*>(&Bts[c * 16 + m][kk * 32 + q * 8]);
        acc[c] = MFMA16(af, bf, acc[c]);
      }
    }
  }
#pragma unroll
  for (int r2 = 0; r2 < 4; ++r2)
#pragma unroll
    for (int c = 0; c < 4; ++c)
      C[(long)(m0 + wv * 16 + q * 4 + r2) * QKVN + n0 + c * 16 + m] = (__bf16)acc[c][r2];
}

// ---------------------------------------------------------------------------
// K2: kf-features with SWAPPED operands (validated round 10).
// Permuted feature layout col' = c*32 + q*8 + r + 4*neg (contraction-invariant,
// matched by flash's qf fragments).
// ---------------------------------------------------------------------------
__global__ __launch_bounds__(256) void features_mfma(const __bf16* __restrict__ qkv,
                                                     const __bf16* __restrict__ projT,
                                                     const __bf16* __restrict__ pi0,
                                                     const __bf16* __restrict__ pi1,
                                                     __bf16* __restrict__ kf) {
  const int l0 = blockIdx.x * 64;
  const int bh = blockIdx.y;
  const int h = bh & 7, b = bh >> 3;
  const int tid = threadIdx.x, lane = tid & 63, wv = tid >> 6;
  const int m = lane & 15, q = lane >> 4;
  __shared__ __bf16 As[2][64][72];   // k1 / k2 tiles: 64 l-rows x 64 d

  {
    const int r = tid >> 2, c0 = (tid & 3) * 16;
    const __bf16* ap = qkv + (long)((l0 + r) * B_SZ + b) * QKVN + h * 256 + 64 + c0;
#pragma unroll
    for (int t2 = 0; t2 < 2; ++t2) {
      *reinterpret_cast<bf16x8*>(&As[t2][r][c0]) =
          *reinterpret_cast<const bf16x8*>(ap + t2 * 64);
      *reinterpret_cast<bf16x8*>(&As[t2][r][c0 + 8]) =
          *reinterpret_cast<const bf16x8*>(ap + t2 * 64 + 8);
    }
  }
  const int l = l0 + wv * 16 + m;          // this thread's sequence row
  const float p0w = (float)pi0[h * 256 + l];
  const float p1w = (float)pi1[h * 256 + l];
  const float SQ = 0.35355339f;            // 64^-0.25
  const float SK2 = 0.24748737f;           // 0.7 * 64^-0.25
  __syncthreads();

  f32x4 acc1[16], acc2[16];
#pragma unroll
  for (int c = 0; c < 16; ++c) {
    acc1[c] = f32x4{0.f, 0.f, 0.f, 0.f};
    acc2[c] = f32x4{0.f, 0.f, 0.f, 0.f};
  }
#pragma unroll
  for (int kk = 0; kk < 2; ++kk) {
    const bf16x8 x1 = *reinterpret_cast<const bf16x8*>(&As[0][wv * 16 + m][kk * 32 + q * 8]);
    const bf16x8 x2 = *reinterpret_cast<const bf16x8*>(&As[1][wv * 16 + m][kk * 32 + q * 8]);
#pragma unroll
    for (int c = 0; c < 16; ++c) {
      const bf16x8 wf =
          *reinterpret_cast<const bf16x8*>(projT + (long)(c * 16 + m) * 64 + kk * 32 + q * 8);
      acc1[c] = MFMA16(wf, x1, acc1[c]);   // acc[c][r] = [l=wv*16+m][p=c*16+q*4+r]
      acc2[c] = MFMA16(wf, x2, acc2[c]);
    }
  }
  float mx1 = 0.f, mx2 = 0.f;
#pragma unroll
  for (int c = 0; c < 16; ++c)
#pragma unroll
    for (int r = 0; r < 4; ++r) {
      mx1 = fmaxf(mx1, fabsf(acc1[c][r] * SQ));
      mx2 = fmaxf(mx2, fabsf(acc2[c][r] * SK2));
    }
  mx1 = fmaxf(mx1, __shfl_xor(mx1, 16)); mx1 = fmaxf(mx1, __shfl_xor(mx1, 32));
  mx2 = fmaxf(mx2, __shfl_xor(mx2, 16)); mx2 = fmaxf(mx2, __shfl_xor(mx2, 32));
  const float C21 = __expf(-2.f * mx1);
  const float C22 = __expf(-2.f * mx2);
  float sm1 = 0.f, sm2 = 0.f;
#pragma unroll
  for (int c = 0; c < 16; ++c)
#pragma unroll
    for (int r = 0; r < 4; ++r) {
      const float e11 = __expf(acc1[c][r] * SQ - mx1);
      const float e12 = __expf(acc2[c][r] * SK2 - mx2);
      sm1 += e11 + C21 * __builtin_amdgcn_rcpf(e11);
      sm2 += e12 + C22 * __builtin_amdgcn_rcpf(e12);
      acc1[c][r] = e11;
      acc2[c][r] = e12;
    }
  sm1 += __shfl_xor(sm1, 16); sm1 += __shfl_xor(sm1, 32);
  sm2 += __shfl_xor(sm2, 16); sm2 += __shfl_xor(sm2, 32);
  const float w1 = p0w * __builtin_amdgcn_rcpf(sm1);
  const float w2 = p1w * __builtin_amdgcn_rcpf(sm2);
  const float K1 = C21 * w1, K2 = C22 * w2;
  __bf16* op = kf + ((long)bh * 256 + l) * FD;
#pragma unroll
  for (int c = 0; c < 16; ++c) {
    bf16x8 v;
#pragma unroll
    for (int r = 0; r < 4; ++r) {
      v[r]     = (__bf16)(w1 * acc1[c][r] + w2 * acc2[c][r]);
      v[4 + r] = (__bf16)(K1 * __builtin_amdgcn_rcpf(acc1[c][r]) +
                          K2 * __builtin_amdgcn_rcpf(acc2[c][r]));
    }
    *reinterpret_cast<bf16x8*>(op + c * 32 + q * 8) = v;
  }
}

// ---------------------------------------------------------------------------
// K2b: pack V transposed per head: vt[bh][d][s] (validated).
// ---------------------------------------------------------------------------
__global__ __launch_bounds__(256) void vpack(const __bf16* __restrict__ qkv,
                                             __bf16* __restrict__ vt) {
  const int s0 = blockIdx.x * 64;
  const int bh = blockIdx.y;
  const int h = bh & 7, b = bh >> 3;
  __shared__ __bf16 T[64][72];
  const int tid = threadIdx.x;
  {
    const int s = tid >> 2, d0 = (tid & 3) * 16;
    const __bf16* vp = qkv + ((long)((s0 + s) * B_SZ + b)) * QKVN + h * 256 + 192 + d0;
#pragma unroll
    for (int j = 0; j < 16; ++j) T[d0 + j][s] = vp[j];
  }
  __syncthreads();
  {
    const int d = tid >> 2, sc = (tid & 3) * 16;
    __bf16* op = vt + ((long)bh * 64 + d) * 256 + s0 + sc;
    *reinterpret_cast<bf16x8*>(op)     = *reinterpret_cast<const bf16x8*>(&T[d][sc]);
    *reinterpret_cast<bf16x8*>(op + 8) = *reinterpret_cast<const bf16x8*>(&T[d][sc + 8]);
  }
}

// ---------------------------------------------------------------------------
// K3: flash, round 11: BARRIER-FREE, fully wave-independent.
// - K/V fragment addresses are wv-invariant: all 4 waves read identical data,
//   so B-operands load DIRECTLY from global (L1/L2-resident; kf XCD-local via
//   id%8==bh%8). No Kc/Vt LDS staging, no __syncthreads anywhere.
// - Pt transpose roundtrip is wave-private (rows [16wv,16wv+16)) -> only the
//   compiler's lgkmcnt ordering is needed.
// - denominator: f32 masked row-sum of s + 4 shfl_xor (drops ones-row, 5th
//   accumulator, zero-fill).
// - id -> (bh=id&255, t=id>>8): mixed-t per CU (balance), same-XCD per bh.
// LDS = 9.2 KB; launch_bounds(256,3) caps VGPR at 168 (qT=64 + pipeline).
// ---------------------------------------------------------------------------
__global__ __launch_bounds__(256, 3) void flash_mfma(const __bf16* __restrict__ qkv,
                                                     const __bf16* __restrict__ projT,
                                                     const __bf16* __restrict__ kf,
                                                     const __bf16* __restrict__ vt,
                                                     __bf16* __restrict__ att) {
  const int id = blockIdx.x;
  const int bh = id & 255;
  const int t  = id >> 8;
  const int h = bh & 7, b = bh >> 3;
  const int tid = threadIdx.x, lane = tid & 63, wv = tid >> 6;
  const int m = lane & 15, q = lane >> 4;
  __shared__ __bf16 Pt[64][72];          // wave-private rows

  // ---------------- feature phase: qT[16] in-register, no LDS ----------------
  const float SQ = 0.35355339f;          // 64^-0.25
  f32x4 acc[16];
#pragma unroll
  for (int c = 0; c < 16; ++c) acc[c] = f32x4{0.f, 0.f, 0.f, 0.f};
  const __bf16* xb = qkv + (long)((t * 64 + wv * 16 + m) * B_SZ + b) * QKVN + h * 256;
#pragma unroll
  for (int kk = 0; kk < 2; ++kk) {
    const bf16x8 xf = *reinterpret_cast<const bf16x8*>(xb + kk * 32 + q * 8);
#pragma unroll
    for (int c = 0; c < 16; ++c) {
      const bf16x8 wf =
          *reinterpret_cast<const bf16x8*>(projT + (long)(c * 16 + m) * 64 + kk * 32 + q * 8);
      acc[c] = MFMA16(wf, xf, acc[c]);   // acc[c][r] = qf-pre[l=wv*16+m][p=c*16+q*4+r]
    }
  }
  float mx = 0.f;
#pragma unroll
  for (int c = 0; c < 16; ++c)
#pragma unroll
    for (int r = 0; r < 4; ++r) mx = fmaxf(mx, fabsf(acc[c][r] * SQ));
  mx = fmaxf(mx, __shfl_xor(mx, 16));
  mx = fmaxf(mx, __shfl_xor(mx, 32));
  const float C2 = __expf(-2.f * mx);
  float sm = 0.f;
#pragma unroll
  for (int c = 0; c < 16; ++c)
#pragma unroll
    for (int r = 0; r < 4; ++r) {
      const float e1 = __expf(acc[c][r] * SQ - mx);
      sm += e1 + C2 * __builtin_amdgcn_rcpf(e1);
      acc[c][r] = e1;
    }
  sm += __shfl_xor(sm, 16);
  sm += __shfl_xor(sm, 32);
  const float inv = __builtin_amdgcn_rcpf(sm);
  const float K2 = C2 * inv;
  bf16x8 qT[16];                         // A-frags, col' = c*32 + q*8 + (r + 4*neg)
#pragma unroll
  for (int c = 0; c < 16; ++c) {
    bf16x8 v;
#pragma unroll
    for (int r = 0; r < 4; ++r) {
      v[r]     = (__bf16)(acc[c][r] * inv);
      v[4 + r] = (__bf16)(K2 * __builtin_amdgcn_rcpf(acc[c][r]));
    }
    qT[c] = v;
  }

  // ---------------- main loop: barrier-free ----------------
  f32x4 o[4];
#pragma unroll
  for (int i = 0; i < 4; ++i) o[i] = f32x4{0.f, 0.f, 0.f, 0.f};
  float den[4] = {0.f, 0.f, 0.f, 0.f};

  const __bf16* kfb = kf + ((long)bh * 256 + m) * FD + q * 8;
  const __bf16* vtb = vt + ((long)bh * 64 + m) * 256 + q * 8;

  for (int st = 0; st <= t; ++st) {
    const __bf16* kp = kfb + (long)st * 64 * FD;
    f32x4 s[4];
#pragma unroll
    for (int i = 0; i < 4; ++i) s[i] = f32x4{0.f, 0.f, 0.f, 0.f};
#pragma unroll
    for (int g = 0; g < 16; ++g) {       // g = ch*4 + kk; qT order matches
      const int off = (g & 3) * 32 + (g >> 2) * 128;
      const bf16x8 kb0 = *reinterpret_cast<const bf16x8*>(kp + off);
      const bf16x8 kb1 = *reinterpret_cast<const bf16x8*>(kp + 16 * FD + off);
      const bf16x8 kb2 = *reinterpret_cast<const bf16x8*>(kp + 32 * FD + off);
      const bf16x8 kb3 = *reinterpret_cast<const bf16x8*>(kp + 48 * FD + off);
      s[0] = MFMA16(qT[g], kb0, s[0]);
      s[1] = MFMA16(qT[g], kb1, s[1]);
      s[2] = MFMA16(qT[g], kb2, s[2]);
      s[3] = MFMA16(qT[g], kb3, s[3]);
    }
    // V fragments for this step (wv-invariant -> L1 hits across waves)
    bf16x8 vf[8];
#pragma unroll
    for (int c = 0; c < 4; ++c) {
      vf[c]     = *reinterpret_cast<const bf16x8*>(vtb + (c * 16) * 256 + st * 64);
      vf[4 + c] = *reinterpret_cast<const bf16x8*>(vtb + (c * 16) * 256 + st * 64 + 32);
    }
    const bool last = (st == t);
#pragma unroll
    for (int c = 0; c < 4; ++c)
#pragma unroll
      for (int r = 0; r < 4; ++r) {
        const int row = wv * 16 + q * 4 + r, col = c * 16 + m;
        const float v = (last && col > row) ? 0.f : s[c][r];
        den[r] += v;
        Pt[row][col] = (__bf16)v;
      }
#pragma unroll
    for (int kk = 0; kk < 2; ++kk) {
      const bf16x8 pf = *reinterpret_cast<const bf16x8*>(&Pt[wv * 16 + m][kk * 32 + q * 8]);
#pragma unroll
      for (int c = 0; c < 4; ++c)
        o[c] = MFMA16(pf, vf[kk * 4 + c], o[c]);
    }
  }
#pragma unroll
  for (int r = 0; r < 4; ++r) {
    float d = den[r];
    d += __shfl_xor(d, 1); d += __shfl_xor(d, 2);
    d += __shfl_xor(d, 4); d += __shfl_xor(d, 8);
    const float invd = 0.125f / (d + 1e-5f);           // SCALE=64^-0.5, EPS
    const int row = t * 64 + wv * 16 + q * 4 + r;
#pragma unroll
    for (int c = 0; c < 4; ++c)
      att[((long)(row * B_SZ + b)) * DM + h * DH + c * 16 + m] = (__bf16)(o[c][r] * invd);
  }
}

// ---------------------------------------------------------------------------
// K4: xrow = hb + att @ w_o (f32 out), MFMA with register prefetch.
// ---------------------------------------------------------------------------
__global__ __launch_bounds__(256) void gemm_att_wo(const __bf16* __restrict__ A,
                                                   const __bf16* __restrict__ Bt,
                                                   const __bf16* __restrict__ hb,
                                                   float* __restrict__ xrow) {
  __shared__ __bf16 At[64][136];
  __shared__ __bf16 Bts[64][136];
  const int n0 = blockIdx.x * 64, m0 = blockIdx.y * 64;
  const int tid = threadIdx.x, lane = tid & 63, wv = tid >> 6;
  const int m = lane & 15, q = lane >> 4;
  const int r = tid >> 2, c0 = (tid & 3) * 32;
  const __bf16* ap = A + (long)(m0 + r) * DM + c0;
  const __bf16* bp = Bt + (long)(n0 + r) * DM + c0;
  f32x4 acc[4];
#pragma unroll
  for (int i = 0; i < 4; ++i) acc[i] = f32x4{0.f, 0.f, 0.f, 0.f};

  bf16x8 ar[4], br[4];
#pragma unroll
  for (int j = 0; j < 4; ++j) {
    ar[j] = *reinterpret_cast<const bf16x8*>(ap + j * 8);
    br[j] = *reinterpret_cast<const bf16x8*>(bp + j * 8);
  }
  for (int k0 = 0; k0 < DM; k0 += 128) {
    __syncthreads();
#pragma unroll
    for (int j = 0; j < 4; ++j) {
      *reinterpret_cast<bf16x8*>(&At[r][c0 + j * 8]) = ar[j];
      *reinterpret_cast<bf16x8*>(&Bts[r][c0 + j * 8]) = br[j];
    }
    if (k0 + 128 < DM) {
#pragma unroll
      for (int j = 0; j < 4; ++j) {
        ar[j] = *reinterpret_cast<const bf16x8*>(ap + k0 + 128 + j * 8);
        br[j] = *reinterpret_cast<const bf16x8*>(bp + k0 + 128 + j * 8);
      }
    }
    __syncthreads();
#pragma unroll
    for (int kk = 0; kk < 4; ++kk) {
      const bf16x8 af = *reinterpret_cast<const bf16x8*>(&At[wv * 16 + m][kk * 32 + q * 8]);
#pragma unroll
      for (int c = 0; c < 4; ++c) {
        const bf16x8 bf = *reinterpret_cast<const bf16x8*>(&Bts[c * 16 + m][kk * 32 + q * 8]);
        acc[c] = MFMA16(af, bf, acc[c]);
      }
    }
  }
#pragma unroll
  for (int r2 = 0; r2 < 4; ++r2)
#pragma unroll
    for (int c = 0; c < 4; ++c) {
      const long row = m0 + wv * 16 + q * 4 + r2;
      const long col = n0 + c * 16 + m;
      xrow[row * DM + col] = acc[c][r2] + (float)hb[row * DM + col];
    }
}

// ---------------------------------------------------------------------------
// K5: LayerNorm rows of xrow -> out (validated rounds 4-8).
// ---------------------------------------------------------------------------
__global__ __launch_bounds__(256) void ln_out(const float* __restrict__ xrow,
                                              const __bf16* __restrict__ gamma,
                                              const __bf16* __restrict__ beta,
                                              const int* __restrict__ flag,
                                              void* __restrict__ out) {
  const int f32 = flag[0];
  const int r = blockIdx.x;
  const int tid = threadIdx.x;
  __shared__ float red[256];
  const float x0 = xrow[(long)r * DM + tid];
  const float x1 = xrow[(long)r * DM + tid + 256];

  red[tid] = x0 + x1; __syncthreads();
  for (int s = 128; s > 0; s >>= 1) { if (tid < s) red[tid] += red[tid + s]; __syncthreads(); }
  const float mu = red[0] * (1.f / 512.f); __syncthreads();
  red[tid] = x0 * x0 + x1 * x1; __syncthreads();
  for (int s = 128; s > 0; s >>= 1) { if (tid < s) red[tid] += red[tid + s]; __syncthreads(); }
  const float var = red[0] * (1.f / 512.f) - mu * mu; __syncthreads();
  const float rstd = rsqrtf(var + 1e-5f);

  stmix(out, (long)r * DM + tid,
        (x0 - mu) * rstd * (float)gamma[tid] + (float)beta[tid], f32);
  stmix(out, (long)r * DM + tid + 256,
        (x1 - mu) * rstd * (float)gamma[tid + 256] + (float)beta[tid + 256], f32);
}

// ---------------------------------------------------------------------------
extern "C" void kernel_launch(void* const* d_in, const int* in_sizes, int n_in,
                              void* d_out, int out_size, void* d_ws, size_t ws_size,
                              hipStream_t stream) {
  (void)in_sizes; (void)n_in; (void)out_size; (void)ws_size;
  char* ws = (char*)d_ws;
  __bf16* qkv   = (__bf16*)ws;
  int*    flag  = (int*)(ws + 33554432);
  __bf16* wt    = (__bf16*)(ws + 33554688);
  __bf16* wot   = (__bf16*)(ws + 35651840);
  __bf16* att   = (__bf16*)(ws + 36176128);
  __bf16* vt    = (__bf16*)(ws + 44564736);
  __bf16* hb    = (__bf16*)(ws + 52953344);
  __bf16* projT = (__bf16*)(ws + 61341952);
  __bf16* pi0b  = (__bf16*)(ws + 61374720);
  __bf16* pi1b  = (__bf16*)(ws + 61378816);
  __bf16* gamb  = (__bf16*)(ws + 61382912);
  __bf16* betb  = (__bf16*)(ws + 61383936);
  __bf16* kf    = (__bf16*)(ws + 128493824);
  float*  xrow  = (float*)(ws + 61384960);   // free region (old qf slot)

  prep<<<PREP_BLOCKS, 256, 0, stream>>>(d_in[0], d_in[1], d_in[2], d_in[7],
                                        d_in[5], d_in[6], d_in[3], d_in[4],
                                        flag, hb, wt, wot, projT,
                                        pi0b, pi1b, gamb, betb);
  gemm_h_wqkv<<<dim3(32, 128), 256, 0, stream>>>(hb, wt, qkv);
  vpack<<<dim3(4, 256), 256, 0, stream>>>(qkv, vt);
  features_mfma<<<dim3(4, 256), 256, 0, stream>>>(qkv, projT, pi0b, pi1b, kf);
  flash_mfma<<<dim3(1024), 256, 0, stream>>>(qkv, projT, kf, vt, att);
  gemm_att_wo<<<dim3(8, 128), 256, 0, stream>>>(att, wot, hb, xrow);
  ln_out<<<dim3(ROWS), 256, 0, stream>>>(xrow, gamb, betb, flag, d_out);
}

// Round 4
// 231.450 us; speedup vs baseline: 1.2690x; 1.2690x over previous
//
#include <hip/hip_runtime.h>
#include <hip/hip_bf16.h>

// L=256, B=32, H=8, d_head=64, m=256, feature dim 2m=512, D_MODEL=512
#define L_SEQ 256
#define B_SZ  32
#define NH    8
#define DH    64
#define DM    512
#define FD    512
#define PM    256
#define ROWS  8192
#define QKVN  2048

typedef __bf16 bf16x8 __attribute__((ext_vector_type(8)));
typedef float f32x4 __attribute__((ext_vector_type(4)));
#define MFMA16(a, b, c) __builtin_amdgcn_mfma_f32_16x16x32_bf16((a), (b), (c), 0, 0, 0)

static __device__ __forceinline__ void stmix(void* p, long i, float v, int f32) {
  if (f32) ((float*)p)[i] = v;
  else     ((__bf16*)p)[i] = (__bf16)v;
}

// ---------------------------------------------------------------------------
// P0: prep — probe + h-cvt + 3 transposes + tiny cvts + projB fragment pack.
// projB layout (fragment-native): chunk (c,kk) at lane=q*16+m, elem e holds
// projT[p = c*16+m][d = kk*32+q*8+e] = proj[d][p] = T[kk*32+q*8+e][p-n0].
// (round-3 bug: T indices were transposed; fixed round 4.)
// ---------------------------------------------------------------------------
#define PREP_HB   2048
#define PREP_WT   256
#define PREP_WOT  64
#define PREP_PJ   4
#define PREP_TINY 1
#define PREP_BLOCKS (PREP_HB + PREP_WT + PREP_WOT + PREP_PJ + PREP_TINY)

__global__ __launch_bounds__(256) void prep(
    const void* __restrict__ h, const void* __restrict__ wqkv,
    const void* __restrict__ wo, const void* __restrict__ proj,
    const void* __restrict__ pi0, const void* __restrict__ pi1,
    const void* __restrict__ gam, const void* __restrict__ bet,
    int* __restrict__ flag, __bf16* __restrict__ hb, __bf16* __restrict__ wt,
    __bf16* __restrict__ wot, __bf16* __restrict__ projT,
    __bf16* __restrict__ pi0b, __bf16* __restrict__ pi1b,
    __bf16* __restrict__ gamb, __bf16* __restrict__ betb,
    __bf16* __restrict__ projB) {
  __shared__ float T[64][69];
  __shared__ int red[256];
  const int tid = threadIdx.x;
  int cnt = 0;
  {
    const unsigned short* hbits = (const unsigned short*)h;
    for (int i = 0; i < 16; ++i) {
      const unsigned short u = hbits[tid * 16 + i];
      if (((u >> 7) & 0xFF) >= 0xA0) ++cnt;
    }
  }
  red[tid] = cnt; __syncthreads();
  for (int s = 128; s > 0; s >>= 1) { if (tid < s) red[tid] += red[tid + s]; __syncthreads(); }
  const int f32 = (red[0] >= 64) ? 1 : 0;
  __syncthreads();

  const int blk = blockIdx.x;
  if (blk < PREP_HB) {
    const int i = blk * 256 + tid;
    if (f32) {
      const f32x4* s = (const f32x4*)h;
      const f32x4 a = s[i * 2], b = s[i * 2 + 1];
      bf16x8 t;
      t[0] = (__bf16)a[0]; t[1] = (__bf16)a[1]; t[2] = (__bf16)a[2]; t[3] = (__bf16)a[3];
      t[4] = (__bf16)b[0]; t[5] = (__bf16)b[1]; t[6] = (__bf16)b[2]; t[7] = (__bf16)b[3];
      *reinterpret_cast<bf16x8*>(hb + (long)i * 8) = t;
    } else {
      *reinterpret_cast<bf16x8*>(hb + (long)i * 8) = ((const bf16x8*)h)[i];
    }
    return;
  }
  const void* src; __bf16* dst; int M, N, n0, m0;
  int pjx = -1;
  if (blk < PREP_HB + PREP_WT) {
    const int x = blk - PREP_HB;
    src = wqkv; dst = wt; M = 512; N = 2048; n0 = (x & 31) * 64; m0 = (x >> 5) * 64;
  } else if (blk < PREP_HB + PREP_WT + PREP_WOT) {
    const int x = blk - PREP_HB - PREP_WT;
    src = wo; dst = wot; M = 512; N = 512; n0 = (x & 7) * 64; m0 = (x >> 3) * 64;
  } else if (blk < PREP_HB + PREP_WT + PREP_WOT + PREP_PJ) {
    const int x = blk - PREP_HB - PREP_WT - PREP_WOT;
    src = proj; dst = projT; M = 64; N = 256; n0 = x * 64; m0 = 0;
    pjx = x;
  } else {
    if (tid == 0) flag[0] = f32;
    if (f32) {
      const float* s0 = (const float*)pi0; const float* s1 = (const float*)pi1;
      const float* s2 = (const float*)gam; const float* s3 = (const float*)bet;
      for (int i = tid; i < NH * 256; i += 256) { pi0b[i] = (__bf16)s0[i]; pi1b[i] = (__bf16)s1[i]; }
      for (int i = tid; i < DM; i += 256)      { gamb[i] = (__bf16)s2[i]; betb[i] = (__bf16)s3[i]; }
    } else {
      const __bf16* s0 = (const __bf16*)pi0; const __bf16* s1 = (const __bf16*)pi1;
      const __bf16* s2 = (const __bf16*)gam; const __bf16* s3 = (const __bf16*)bet;
      for (int i = tid; i < NH * 256; i += 256) { pi0b[i] = s0[i]; pi1b[i] = s1[i]; }
      for (int i = tid; i < DM; i += 256)      { gamb[i] = s2[i]; betb[i] = s3[i]; }
    }
    return;
  }
  if (f32) {
    const float* s = (const float*)src;
#pragma unroll
    for (int rep = 0; rep < 16; ++rep) {
      const int i = rep * 4 + (tid >> 6), j = tid & 63;
      T[i][j] = s[(long)(m0 + i) * N + n0 + j];
    }
  } else {
    const __bf16* s = (const __bf16*)src;
#pragma unroll
    for (int rep = 0; rep < 16; ++rep) {
      const int i = rep * 4 + (tid >> 6), j = tid & 63;
      T[i][j] = (float)s[(long)(m0 + i) * N + n0 + j];
    }
  }
  __syncthreads();
#pragma unroll
  for (int rep = 0; rep < 16; ++rep) {
    const int i = rep * 4 + (tid >> 6), j = tid & 63;
    dst[(long)(n0 + i) * M + m0 + j] = (__bf16)T[j][i];
  }
  if (pjx >= 0) {
    // fragment-native pack. T[d][p-n0] here (rows = d, cols = feature):
    // chunk c=pjx*4+sub, lane (m,q), elem e := proj[d = kk*32+q*8+e][p = c*16+m]
    //   = T[kk*32 + qq*8 + e][sub*16 + mm]            (FIXED: was transposed)
    const int lane = tid & 63, sub = tid >> 6;
    const int mm = lane & 15, qq = lane >> 4;
#pragma unroll
    for (int kk2 = 0; kk2 < 2; ++kk2) {
      bf16x8 v;
#pragma unroll
      for (int e = 0; e < 8; ++e) v[e] = (__bf16)T[kk2 * 32 + qq * 8 + e][sub * 16 + mm];
      *reinterpret_cast<bf16x8*>(projB + ((pjx * 4 + sub) * 2 + kk2) * 512 + lane * 8) = v;
    }
  }
}

// ---------------------------------------------------------------------------
// K1: qkv = hb @ w_qkv via MFMA with register prefetch (validated rounds 7-8).
// ---------------------------------------------------------------------------
__global__ __launch_bounds__(256) void gemm_h_wqkv(const __bf16* __restrict__ A,
                                                   const __bf16* __restrict__ Bt,
                                                   __bf16* __restrict__ C) {
  __shared__ __bf16 At[64][136];
  __shared__ __bf16 Bts[64][136];
  const int n0 = blockIdx.x * 64, m0 = blockIdx.y * 64;
  const int tid = threadIdx.x, lane = tid & 63, wv = tid >> 6;
  const int m = lane & 15, q = lane >> 4;
  const int r = tid >> 2, c0 = (tid & 3) * 32;
  const __bf16* ap = A + (long)(m0 + r) * DM + c0;
  const __bf16* bp = Bt + (long)(n0 + r) * DM + c0;
  f32x4 acc[4];
#pragma unroll
  for (int i = 0; i < 4; ++i) acc[i] = f32x4{0.f, 0.f, 0.f, 0.f};

  bf16x8 ar[4], br[4];
#pragma unroll
  for (int j = 0; j < 4; ++j) {
    ar[j] = *reinterpret_cast<const bf16x8*>(ap + j * 8);
    br[j] = *reinterpret_cast<const bf16x8*>(bp + j * 8);
  }
  for (int k0 = 0; k0 < DM; k0 += 128) {
    __syncthreads();
#pragma unroll
    for (int j = 0; j < 4; ++j) {
      *reinterpret_cast<bf16x8*>(&At[r][c0 + j * 8]) = ar[j];
      *reinterpret_cast<bf16x8*>(&Bts[r][c0 + j * 8]) = br[j];
    }
    if (k0 + 128 < DM) {
#pragma unroll
      for (int j = 0; j < 4; ++j) {
        ar[j] = *reinterpret_cast<const bf16x8*>(ap + k0 + 128 + j * 8);
        br[j] = *reinterpret_cast<const bf16x8*>(bp + k0 + 128 + j * 8);
      }
    }
    __syncthreads();
#pragma unroll
    for (int kk = 0; kk < 4; ++kk) {
      const bf16x8 af = *reinterpret_cast<const bf16x8*>(&At[wv * 16 + m][kk * 32 + q * 8]);
#pragma unroll
      for (int c = 0; c < 4; ++c) {
        const bf16x8 bf = *reinterpret_cast<const bf16x8*>(&Bts[c * 16 + m][kk * 32 + q * 8]);
        acc[c] = MFMA16(af, bf, acc[c]);
      }
    }
  }
#pragma unroll
  for (int r2 = 0; r2 < 4; ++r2)
#pragma unroll
    for (int c = 0; c < 4; ++c)
      C[(long)(m0 + wv * 16 + q * 4 + r2) * QKVN + n0 + c * 16 + m] = (__bf16)acc[c][r2];
}

// ---------------------------------------------------------------------------
// K2: kf-features, SWAPPED operands + FRAGMENT-NATIVE kf output (round 12).
// kf layout: per bh, 16 l-tiles x 16 feature-blocks, each a 1KB chunk in
// B-fragment lane order: chunk[lt][fb] + lane*8 holds kf[lt*16+m][p-block fb],
// elems e = r+4*neg, col' = fb*32 + q*8 + e.  Both the kf stores here and the
// B-fragment loads in flash are contiguous 1KB per instruction.
// ---------------------------------------------------------------------------
__global__ __launch_bounds__(256) void features_mfma(const __bf16* __restrict__ qkv,
                                                     const __bf16* __restrict__ projB,
                                                     const __bf16* __restrict__ pi0,
                                                     const __bf16* __restrict__ pi1,
                                                     __bf16* __restrict__ kf) {
  const int l0 = blockIdx.x * 64;
  const int bh = blockIdx.y;
  const int h = bh & 7, b = bh >> 3;
  const int tid = threadIdx.x, lane = tid & 63, wv = tid >> 6;
  const int m = lane & 15, q = lane >> 4;
  __shared__ __bf16 As[2][64][72];   // k1 / k2 tiles: 64 l-rows x 64 d

  {
    const int r = tid >> 2, c0 = (tid & 3) * 16;
    const __bf16* ap = qkv + (long)((l0 + r) * B_SZ + b) * QKVN + h * 256 + 64 + c0;
#pragma unroll
    for (int t2 = 0; t2 < 2; ++t2) {
      *reinterpret_cast<bf16x8*>(&As[t2][r][c0]) =
          *reinterpret_cast<const bf16x8*>(ap + t2 * 64);
      *reinterpret_cast<bf16x8*>(&As[t2][r][c0 + 8]) =
          *reinterpret_cast<const bf16x8*>(ap + t2 * 64 + 8);
    }
  }
  const int l = l0 + wv * 16 + m;          // this thread's sequence row
  const float p0w = (float)pi0[h * 256 + l];
  const float p1w = (float)pi1[h * 256 + l];
  const float SQ = 0.35355339f;            // 64^-0.25
  const float SK2 = 0.24748737f;           // 0.7 * 64^-0.25
  __syncthreads();

  f32x4 acc1[16], acc2[16];
#pragma unroll
  for (int c = 0; c < 16; ++c) {
    acc1[c] = f32x4{0.f, 0.f, 0.f, 0.f};
    acc2[c] = f32x4{0.f, 0.f, 0.f, 0.f};
  }
#pragma unroll
  for (int kk = 0; kk < 2; ++kk) {
    const bf16x8 x1 = *reinterpret_cast<const bf16x8*>(&As[0][wv * 16 + m][kk * 32 + q * 8]);
    const bf16x8 x2 = *reinterpret_cast<const bf16x8*>(&As[1][wv * 16 + m][kk * 32 + q * 8]);
#pragma unroll
    for (int c = 0; c < 16; ++c) {
      const bf16x8 wf =
          *reinterpret_cast<const bf16x8*>(projB + (c * 2 + kk) * 512 + lane * 8);
      acc1[c] = MFMA16(wf, x1, acc1[c]);   // acc[c][r] = [l=wv*16+m][p=c*16+q*4+r]
      acc2[c] = MFMA16(wf, x2, acc2[c]);
    }
  }
  float mx1 = 0.f, mx2 = 0.f;
#pragma unroll
  for (int c = 0; c < 16; ++c)
#pragma unroll
    for (int r = 0; r < 4; ++r) {
      mx1 = fmaxf(mx1, fabsf(acc1[c][r] * SQ));
      mx2 = fmaxf(mx2, fabsf(acc2[c][r] * SK2));
    }
  mx1 = fmaxf(mx1, __shfl_xor(mx1, 16)); mx1 = fmaxf(mx1, __shfl_xor(mx1, 32));
  mx2 = fmaxf(mx2, __shfl_xor(mx2, 16)); mx2 = fmaxf(mx2, __shfl_xor(mx2, 32));
  const float C21 = __expf(-2.f * mx1);
  const float C22 = __expf(-2.f * mx2);
  float sm1 = 0.f, sm2 = 0.f;
#pragma unroll
  for (int c = 0; c < 16; ++c)
#pragma unroll
    for (int r = 0; r < 4; ++r) {
      const float e11 = __expf(acc1[c][r] * SQ - mx1);
      const float e12 = __expf(acc2[c][r] * SK2 - mx2);
      sm1 += e11 + C21 * __builtin_amdgcn_rcpf(e11);
      sm2 += e12 + C22 * __builtin_amdgcn_rcpf(e12);
      acc1[c][r] = e11;
      acc2[c][r] = e12;
    }
  sm1 += __shfl_xor(sm1, 16); sm1 += __shfl_xor(sm1, 32);
  sm2 += __shfl_xor(sm2, 16); sm2 += __shfl_xor(sm2, 32);
  const float w1 = p0w * __builtin_amdgcn_rcpf(sm1);
  const float w2 = p1w * __builtin_amdgcn_rcpf(sm2);
  const float K1 = C21 * w1, K2 = C22 * w2;
  // fragment-native store: chunk [lt = l>>4][c], lane offset = lane*8
  __bf16* op = kf + (((long)bh * 16 + (l >> 4)) * 16) * 512 + lane * 8;
#pragma unroll
  for (int c = 0; c < 16; ++c) {
    bf16x8 v;
#pragma unroll
    for (int r = 0; r < 4; ++r) {
      v[r]     = (__bf16)(w1 * acc1[c][r] + w2 * acc2[c][r]);
      v[4 + r] = (__bf16)(K1 * __builtin_amdgcn_rcpf(acc1[c][r]) +
                          K2 * __builtin_amdgcn_rcpf(acc2[c][r]));
    }
    *reinterpret_cast<bf16x8*>(op + c * 512) = v;
  }
}

// ---------------------------------------------------------------------------
// K2b: pack V into PV-fragment-native layout (round 12).
// chunk (st,kk,c): V[s = st*64+kk*32+q*8+e][d = c*16+m] at
// vt + ((bh*8 + st*2 + kk)*4 + c)*512 + lane*8, lane = q*16+m.  8 MB total.
// ---------------------------------------------------------------------------
__global__ __launch_bounds__(256) void vpack(const __bf16* __restrict__ qkv,
                                             __bf16* __restrict__ vt) {
  const int st = blockIdx.x;
  const int s0 = st * 64;
  const int bh = blockIdx.y;
  const int h = bh & 7, b = bh >> 3;
  __shared__ __bf16 T[64][72];           // [d][s], row stride 144B (16B-mult)
  const int tid = threadIdx.x;
  {
    const int s = tid >> 2, d0 = (tid & 3) * 16;
    const __bf16* vp = qkv + ((long)((s0 + s) * B_SZ + b)) * QKVN + h * 256 + 192 + d0;
#pragma unroll
    for (int j = 0; j < 16; ++j) T[d0 + j][s] = vp[j];
  }
  __syncthreads();
  {
    const int lane = tid & 63, c2 = tid >> 6;
    const int m = lane & 15, q = lane >> 4;
    const int d = c2 * 16 + m;
#pragma unroll
    for (int kk = 0; kk < 2; ++kk) {
      const bf16x8 v = *reinterpret_cast<const bf16x8*>(&T[d][kk * 32 + q * 8]);
      *reinterpret_cast<bf16x8*>(vt + (((long)bh * 8 + st * 2 + kk) * 4 + c2) * 512 + lane * 8) = v;
    }
  }
}

// ---------------------------------------------------------------------------
// K3: flash, round 12: barrier-free + FRAGMENT-NATIVE coalesced loads.
// All B-operands (kf chunks, V chunks, projB) load as base + lane*16B —
// one contiguous 1KB transaction per instruction (was 16-segment gathers,
// the round-11 regression). Pt transpose roundtrip stays wave-private LDS.
// id -> bh = id&255 (id%8==bh%8: same-XCD kf reuse), t mixed per round.
// ---------------------------------------------------------------------------
__global__ __launch_bounds__(256, 3) void flash_mfma(const __bf16* __restrict__ qkv,
                                                     const __bf16* __restrict__ projB,
                                                     const __bf16* __restrict__ kf,
                                                     const __bf16* __restrict__ vt,
                                                     __bf16* __restrict__ att) {
  const int id = blockIdx.x;
  const int bh = id & 255;
  const int t  = ((id >> 8) + id) & 3;   // bijective per bh, mixed per round
  const int h = bh & 7, b = bh >> 3;
  const int tid = threadIdx.x, lane = tid & 63, wv = tid >> 6;
  const int m = lane & 15, q = lane >> 4;
  __shared__ __bf16 Pt[64][72];          // wave-private rows

  // ---------------- feature phase: qT[16] in-register ----------------
  const float SQ = 0.35355339f;          // 64^-0.25
  f32x4 acc[16];
#pragma unroll
  for (int c = 0; c < 16; ++c) acc[c] = f32x4{0.f, 0.f, 0.f, 0.f};
  const __bf16* xb = qkv + (long)((t * 64 + wv * 16 + m) * B_SZ + b) * QKVN + h * 256;
#pragma unroll
  for (int kk = 0; kk < 2; ++kk) {
    const bf16x8 xf = *reinterpret_cast<const bf16x8*>(xb + kk * 32 + q * 8);
#pragma unroll
    for (int c = 0; c < 16; ++c) {
      const bf16x8 wf =
          *reinterpret_cast<const bf16x8*>(projB + (c * 2 + kk) * 512 + lane * 8);
      acc[c] = MFMA16(wf, xf, acc[c]);   // acc[c][r] = qf-pre[l=wv*16+m][p=c*16+q*4+r]
    }
  }
  float mx = 0.f;
#pragma unroll
  for (int c = 0; c < 16; ++c)
#pragma unroll
    for (int r = 0; r < 4; ++r) mx = fmaxf(mx, fabsf(acc[c][r] * SQ));
  mx = fmaxf(mx, __shfl_xor(mx, 16));
  mx = fmaxf(mx, __shfl_xor(mx, 32));
  const float C2 = __expf(-2.f * mx);
  float sm = 0.f;
#pragma unroll
  for (int c = 0; c < 16; ++c)
#pragma unroll
    for (int r = 0; r < 4; ++r) {
      const float e1 = __expf(acc[c][r] * SQ - mx);
      sm += e1 + C2 * __builtin_amdgcn_rcpf(e1);
      acc[c][r] = e1;
    }
  sm += __shfl_xor(sm, 16);
  sm += __shfl_xor(sm, 32);
  const float inv = __builtin_amdgcn_rcpf(sm);
  const float K2 = C2 * inv;
  bf16x8 qT[16];                         // A-frags, k = q*8 + (r + 4*neg)
#pragma unroll
  for (int c = 0; c < 16; ++c) {
    bf16x8 v;
#pragma unroll
    for (int r = 0; r < 4; ++r) {
      v[r]     = (__bf16)(acc[c][r] * inv);
      v[4 + r] = (__bf16)(K2 * __builtin_amdgcn_rcpf(acc[c][r]));
    }
    qT[c] = v;
  }

  // ---------------- main loop: barrier-free, coalesced fragments ----------------
  f32x4 o[4];
#pragma unroll
  for (int i = 0; i < 4; ++i) o[i] = f32x4{0.f, 0.f, 0.f, 0.f};
  float den[4] = {0.f, 0.f, 0.f, 0.f};

  const __bf16* kfb = kf + (long)bh * (16 * 16 * 512) + lane * 8;
  const __bf16* vtb = vt + (long)bh * (8 * 4 * 512) + lane * 8;

  for (int st = 0; st <= t; ++st) {
    f32x4 s[4];
#pragma unroll
    for (int i = 0; i < 4; ++i) s[i] = f32x4{0.f, 0.f, 0.f, 0.f};
#pragma unroll
    for (int g = 0; g < 16; ++g) {
      const __bf16* kp = kfb + ((long)(st * 4) * 16 + g) * 512;
      const bf16x8 kb0 = *reinterpret_cast<const bf16x8*>(kp);
      const bf16x8 kb1 = *reinterpret_cast<const bf16x8*>(kp + 16 * 512);
      const bf16x8 kb2 = *reinterpret_cast<const bf16x8*>(kp + 32 * 512);
      const bf16x8 kb3 = *reinterpret_cast<const bf16x8*>(kp + 48 * 512);
      s[0] = MFMA16(qT[g], kb0, s[0]);
      s[1] = MFMA16(qT[g], kb1, s[1]);
      s[2] = MFMA16(qT[g], kb2, s[2]);
      s[3] = MFMA16(qT[g], kb3, s[3]);
    }
    // V fragments for this step (coalesced 1KB chunks)
    bf16x8 vf[8];
#pragma unroll
    for (int kk = 0; kk < 2; ++kk)
#pragma unroll
      for (int c = 0; c < 4; ++c)
        vf[kk * 4 + c] =
            *reinterpret_cast<const bf16x8*>(vtb + (((long)st * 2 + kk) * 4 + c) * 512);
    const bool last = (st == t);
#pragma unroll
    for (int c = 0; c < 4; ++c)
#pragma unroll
      for (int r = 0; r < 4; ++r) {
        const int row = wv * 16 + q * 4 + r, col = c * 16 + m;
        const float v = (last && col > row) ? 0.f : s[c][r];
        den[r] += v;
        Pt[row][col] = (__bf16)v;
      }
#pragma unroll
    for (int kk = 0; kk < 2; ++kk) {
      const bf16x8 pf = *reinterpret_cast<const bf16x8*>(&Pt[wv * 16 + m][kk * 32 + q * 8]);
#pragma unroll
      for (int c = 0; c < 4; ++c)
        o[c] = MFMA16(pf, vf[kk * 4 + c], o[c]);
    }
  }
#pragma unroll
  for (int r = 0; r < 4; ++r) {
    float d = den[r];
    d += __shfl_xor(d, 1); d += __shfl_xor(d, 2);
    d += __shfl_xor(d, 4); d += __shfl_xor(d, 8);
    const float invd = 0.125f / (d + 1e-5f);           // SCALE=64^-0.5, EPS
    const int row = t * 64 + wv * 16 + q * 4 + r;
#pragma unroll
    for (int c = 0; c < 4; ++c)
      att[((long)(row * B_SZ + b)) * DM + h * DH + c * 16 + m] = (__bf16)(o[c][r] * invd);
  }
}

// ---------------------------------------------------------------------------
// K4: xrow = hb + att @ w_o (f32 out), MFMA with register prefetch.
// ---------------------------------------------------------------------------
__global__ __launch_bounds__(256) void gemm_att_wo(const __bf16* __restrict__ A,
                                                   const __bf16* __restrict__ Bt,
                                                   const __bf16* __restrict__ hb,
                                                   float* __restrict__ xrow) {
  __shared__ __bf16 At[64][136];
  __shared__ __bf16 Bts[64][136];
  const int n0 = blockIdx.x * 64, m0 = blockIdx.y * 64;
  const int tid = threadIdx.x, lane = tid & 63, wv = tid >> 6;
  const int m = lane & 15, q = lane >> 4;
  const int r = tid >> 2, c0 = (tid & 3) * 32;
  const __bf16* ap = A + (long)(m0 + r) * DM + c0;
  const __bf16* bp = Bt + (long)(n0 + r) * DM + c0;
  f32x4 acc[4];
#pragma unroll
  for (int i = 0; i < 4; ++i) acc[i] = f32x4{0.f, 0.f, 0.f, 0.f};

  bf16x8 ar[4], br[4];
#pragma unroll
  for (int j = 0; j < 4; ++j) {
    ar[j] = *reinterpret_cast<const bf16x8*>(ap + j * 8);
    br[j] = *reinterpret_cast<const bf16x8*>(bp + j * 8);
  }
  for (int k0 = 0; k0 < DM; k0 += 128) {
    __syncthreads();
#pragma unroll
    for (int j = 0; j < 4; ++j) {
      *reinterpret_cast<bf16x8*>(&At[r][c0 + j * 8]) = ar[j];
      *reinterpret_cast<bf16x8*>(&Bts[r][c0 + j * 8]) = br[j];
    }
    if (k0 + 128 < DM) {
#pragma unroll
      for (int j = 0; j < 4; ++j) {
        ar[j] = *reinterpret_cast<const bf16x8*>(ap + k0 + 128 + j * 8);
        br[j] = *reinterpret_cast<const bf16x8*>(bp + k0 + 128 + j * 8);
      }
    }
    __syncthreads();
#pragma unroll
    for (int kk = 0; kk < 4; ++kk) {
      const bf16x8 af = *reinterpret_cast<const bf16x8*>(&At[wv * 16 + m][kk * 32 + q * 8]);
#pragma unroll
      for (int c = 0; c < 4; ++c) {
        const bf16x8 bf = *reinterpret_cast<const bf16x8*>(&Bts[c * 16 + m][kk * 32 + q * 8]);
        acc[c] = MFMA16(af, bf, acc[c]);
      }
    }
  }
#pragma unroll
  for (int r2 = 0; r2 < 4; ++r2)
#pragma unroll
    for (int c = 0; c < 4; ++c) {
      const long row = m0 + wv * 16 + q * 4 + r2;
      const long col = n0 + c * 16 + m;
      xrow[row * DM + col] = acc[c][r2] + (float)hb[row * DM + col];
    }
}

// ---------------------------------------------------------------------------
// K5: LayerNorm rows of xrow -> out (validated rounds 4-8).
// ---------------------------------------------------------------------------
__global__ __launch_bounds__(256) void ln_out(const float* __restrict__ xrow,
                                              const __bf16* __restrict__ gamma,
                                              const __bf16* __restrict__ beta,
                                              const int* __restrict__ flag,
                                              void* __restrict__ out) {
  const int f32 = flag[0];
  const int r = blockIdx.x;
  const int tid = threadIdx.x;
  __shared__ float red[256];
  const float x0 = xrow[(long)r * DM + tid];
  const float x1 = xrow[(long)r * DM + tid + 256];

  red[tid] = x0 + x1; __syncthreads();
  for (int s = 128; s > 0; s >>= 1) { if (tid < s) red[tid] += red[tid + s]; __syncthreads(); }
  const float mu = red[0] * (1.f / 512.f); __syncthreads();
  red[tid] = x0 * x0 + x1 * x1; __syncthreads();
  for (int s = 128; s > 0; s >>= 1) { if (tid < s) red[tid] += red[tid + s]; __syncthreads(); }
  const float var = red[0] * (1.f / 512.f) - mu * mu; __syncthreads();
  const float rstd = rsqrtf(var + 1e-5f);

  stmix(out, (long)r * DM + tid,
        (x0 - mu) * rstd * (float)gamma[tid] + (float)beta[tid], f32);
  stmix(out, (long)r * DM + tid + 256,
        (x1 - mu) * rstd * (float)gamma[tid + 256] + (float)beta[tid + 256], f32);
}

// ---------------------------------------------------------------------------
extern "C" void kernel_launch(void* const* d_in, const int* in_sizes, int n_in,
                              void* d_out, int out_size, void* d_ws, size_t ws_size,
                              hipStream_t stream) {
  (void)in_sizes; (void)n_in; (void)out_size; (void)ws_size;
  char* ws = (char*)d_ws;
  __bf16* qkv   = (__bf16*)ws;
  int*    flag  = (int*)(ws + 33554432);
  __bf16* wt    = (__bf16*)(ws + 33554688);
  __bf16* wot   = (__bf16*)(ws + 35651840);
  __bf16* att   = (__bf16*)(ws + 36176128);
  __bf16* vt    = (__bf16*)(ws + 44564736);
  __bf16* hb    = (__bf16*)(ws + 52953344);
  __bf16* projT = (__bf16*)(ws + 61341952);
  __bf16* pi0b  = (__bf16*)(ws + 61374720);
  __bf16* pi1b  = (__bf16*)(ws + 61378816);
  __bf16* gamb  = (__bf16*)(ws + 61382912);
  __bf16* betb  = (__bf16*)(ws + 61383936);
  float*  xrow  = (float*)(ws + 61384960);   // 16 MB
  __bf16* projB = (__bf16*)(ws + 78163968);  // 32 KB fragment-native proj
  __bf16* kf    = (__bf16*)(ws + 128493824);

  prep<<<PREP_BLOCKS, 256, 0, stream>>>(d_in[0], d_in[1], d_in[2], d_in[7],
                                        d_in[5], d_in[6], d_in[3], d_in[4],
                                        flag, hb, wt, wot, projT,
                                        pi0b, pi1b, gamb, betb, projB);
  gemm_h_wqkv<<<dim3(32, 128), 256, 0, stream>>>(hb, wt, qkv);
  vpack<<<dim3(4, 256), 256, 0, stream>>>(qkv, vt);
  features_mfma<<<dim3(4, 256), 256, 0, stream>>>(qkv, projB, pi0b, pi1b, kf);
  flash_mfma<<<dim3(1024), 256, 0, stream>>>(qkv, projB, kf, vt, att);
  gemm_att_wo<<<dim3(8, 128), 256, 0, stream>>>(att, wot, hb, xrow);
  ln_out<<<dim3(ROWS), 256, 0, stream>>>(xrow, gamb, betb, flag, d_out);
}

// Round 5
// 223.945 us; speedup vs baseline: 1.3115x; 1.0335x over previous
//
#include <hip/hip_runtime.h>
#include <hip/hip_bf16.h>

// L=256, B=32, H=8, d_head=64, m=256, feature dim 2m=512, D_MODEL=512
#define L_SEQ 256
#define B_SZ  32
#define NH    8
#define DH    64
#define DM    512
#define FD    512
#define PM    256
#define ROWS  8192
#define QKVN  2048

typedef __bf16 bf16x8 __attribute__((ext_vector_type(8)));
typedef float f32x4 __attribute__((ext_vector_type(4)));
#define MFMA16(a, b, c) __builtin_amdgcn_mfma_f32_16x16x32_bf16((a), (b), (c), 0, 0, 0)

static __device__ __forceinline__ void stmix(void* p, long i, float v, int f32) {
  if (f32) ((float*)p)[i] = v;
  else     ((__bf16*)p)[i] = (__bf16)v;
}

// ---------------------------------------------------------------------------
// P0: prep — probe + h-cvt + 3 transposes + tiny cvts + projB fragment pack.
// projB layout (fragment-native): chunk (c,kk) at lane=q*16+m, elem e holds
// projT[p = c*16+m][d = kk*32+q*8+e] = proj[d][p] = T[kk*32+q*8+e][p-n0].
// ---------------------------------------------------------------------------
#define PREP_HB   2048
#define PREP_WT   256
#define PREP_WOT  64
#define PREP_PJ   4
#define PREP_TINY 1
#define PREP_BLOCKS (PREP_HB + PREP_WT + PREP_WOT + PREP_PJ + PREP_TINY)

__global__ __launch_bounds__(256) void prep(
    const void* __restrict__ h, const void* __restrict__ wqkv,
    const void* __restrict__ wo, const void* __restrict__ proj,
    const void* __restrict__ pi0, const void* __restrict__ pi1,
    const void* __restrict__ gam, const void* __restrict__ bet,
    int* __restrict__ flag, __bf16* __restrict__ hb, __bf16* __restrict__ wt,
    __bf16* __restrict__ wot, __bf16* __restrict__ projT,
    __bf16* __restrict__ pi0b, __bf16* __restrict__ pi1b,
    __bf16* __restrict__ gamb, __bf16* __restrict__ betb,
    __bf16* __restrict__ projB) {
  __shared__ float T[64][69];
  __shared__ int red[256];
  const int tid = threadIdx.x;
  int cnt = 0;
  {
    const unsigned short* hbits = (const unsigned short*)h;
    for (int i = 0; i < 16; ++i) {
      const unsigned short u = hbits[tid * 16 + i];
      if (((u >> 7) & 0xFF) >= 0xA0) ++cnt;
    }
  }
  red[tid] = cnt; __syncthreads();
  for (int s = 128; s > 0; s >>= 1) { if (tid < s) red[tid] += red[tid + s]; __syncthreads(); }
  const int f32 = (red[0] >= 64) ? 1 : 0;
  __syncthreads();

  const int blk = blockIdx.x;
  if (blk < PREP_HB) {
    const int i = blk * 256 + tid;
    if (f32) {
      const f32x4* s = (const f32x4*)h;
      const f32x4 a = s[i * 2], b = s[i * 2 + 1];
      bf16x8 t;
      t[0] = (__bf16)a[0]; t[1] = (__bf16)a[1]; t[2] = (__bf16)a[2]; t[3] = (__bf16)a[3];
      t[4] = (__bf16)b[0]; t[5] = (__bf16)b[1]; t[6] = (__bf16)b[2]; t[7] = (__bf16)b[3];
      *reinterpret_cast<bf16x8*>(hb + (long)i * 8) = t;
    } else {
      *reinterpret_cast<bf16x8*>(hb + (long)i * 8) = ((const bf16x8*)h)[i];
    }
    return;
  }
  const void* src; __bf16* dst; int M, N, n0, m0;
  int pjx = -1;
  if (blk < PREP_HB + PREP_WT) {
    const int x = blk - PREP_HB;
    src = wqkv; dst = wt; M = 512; N = 2048; n0 = (x & 31) * 64; m0 = (x >> 5) * 64;
  } else if (blk < PREP_HB + PREP_WT + PREP_WOT) {
    const int x = blk - PREP_HB - PREP_WT;
    src = wo; dst = wot; M = 512; N = 512; n0 = (x & 7) * 64; m0 = (x >> 3) * 64;
  } else if (blk < PREP_HB + PREP_WT + PREP_WOT + PREP_PJ) {
    const int x = blk - PREP_HB - PREP_WT - PREP_WOT;
    src = proj; dst = projT; M = 64; N = 256; n0 = x * 64; m0 = 0;
    pjx = x;
  } else {
    if (tid == 0) flag[0] = f32;
    if (f32) {
      const float* s0 = (const float*)pi0; const float* s1 = (const float*)pi1;
      const float* s2 = (const float*)gam; const float* s3 = (const float*)bet;
      for (int i = tid; i < NH * 256; i += 256) { pi0b[i] = (__bf16)s0[i]; pi1b[i] = (__bf16)s1[i]; }
      for (int i = tid; i < DM; i += 256)      { gamb[i] = (__bf16)s2[i]; betb[i] = (__bf16)s3[i]; }
    } else {
      const __bf16* s0 = (const __bf16*)pi0; const __bf16* s1 = (const __bf16*)pi1;
      const __bf16* s2 = (const __bf16*)gam; const __bf16* s3 = (const __bf16*)bet;
      for (int i = tid; i < NH * 256; i += 256) { pi0b[i] = s0[i]; pi1b[i] = s1[i]; }
      for (int i = tid; i < DM; i += 256)      { gamb[i] = s2[i]; betb[i] = s3[i]; }
    }
    return;
  }
  if (f32) {
    const float* s = (const float*)src;
#pragma unroll
    for (int rep = 0; rep < 16; ++rep) {
      const int i = rep * 4 + (tid >> 6), j = tid & 63;
      T[i][j] = s[(long)(m0 + i) * N + n0 + j];
    }
  } else {
    const __bf16* s = (const __bf16*)src;
#pragma unroll
    for (int rep = 0; rep < 16; ++rep) {
      const int i = rep * 4 + (tid >> 6), j = tid & 63;
      T[i][j] = (float)s[(long)(m0 + i) * N + n0 + j];
    }
  }
  __syncthreads();
#pragma unroll
  for (int rep = 0; rep < 16; ++rep) {
    const int i = rep * 4 + (tid >> 6), j = tid & 63;
    dst[(long)(n0 + i) * M + m0 + j] = (__bf16)T[j][i];
  }
  if (pjx >= 0) {
    // fragment-native pack. T[d][p-n0] here (rows = d, cols = feature):
    // chunk c=pjx*4+sub, lane (m,q), elem e := proj[d = kk*32+q*8+e][p = c*16+m]
    const int lane = tid & 63, sub = tid >> 6;
    const int mm = lane & 15, qq = lane >> 4;
#pragma unroll
    for (int kk2 = 0; kk2 < 2; ++kk2) {
      bf16x8 v;
#pragma unroll
      for (int e = 0; e < 8; ++e) v[e] = (__bf16)T[kk2 * 32 + qq * 8 + e][sub * 16 + mm];
      *reinterpret_cast<bf16x8*>(projB + ((pjx * 4 + sub) * 2 + kk2) * 512 + lane * 8) = v;
    }
  }
}

// ---------------------------------------------------------------------------
// K1: qkv = hb @ w_qkv, round 13: 128x128 tile, BK=64, per-wave 64x64 output.
// LDS reads/MFMA 1.25KB -> 0.5KB; staged L2 traffic 512MB -> 256MB.
// Same validated reg-prefetch 2-barrier structure as rounds 7-12.
// ---------------------------------------------------------------------------
__global__ __launch_bounds__(256) void gemm_h_wqkv(const __bf16* __restrict__ A,
                                                   const __bf16* __restrict__ Bt,
                                                   __bf16* __restrict__ C) {
  __shared__ __bf16 At[128][72];
  __shared__ __bf16 Bts[128][72];
  const int n0 = blockIdx.x * 128, m0 = blockIdx.y * 128;
  const int tid = threadIdx.x, lane = tid & 63, wv = tid >> 6;
  const int m = lane & 15, q = lane >> 4;
  const int wr = (wv >> 1) * 64, wc = (wv & 1) * 64;
  const int r = tid >> 1, c0 = (tid & 1) * 32;
  const __bf16* ap = A + (long)(m0 + r) * DM + c0;
  const __bf16* bp = Bt + (long)(n0 + r) * DM + c0;
  f32x4 acc[4][4];
#pragma unroll
  for (int i = 0; i < 4; ++i)
#pragma unroll
    for (int j = 0; j < 4; ++j) acc[i][j] = f32x4{0.f, 0.f, 0.f, 0.f};

  bf16x8 ar[4], br[4];
#pragma unroll
  for (int j = 0; j < 4; ++j) {
    ar[j] = *reinterpret_cast<const bf16x8*>(ap + j * 8);
    br[j] = *reinterpret_cast<const bf16x8*>(bp + j * 8);
  }
  for (int k0 = 0; k0 < DM; k0 += 64) {
    __syncthreads();
#pragma unroll
    for (int j = 0; j < 4; ++j) {
      *reinterpret_cast<bf16x8*>(&At[r][c0 + j * 8]) = ar[j];
      *reinterpret_cast<bf16x8*>(&Bts[r][c0 + j * 8]) = br[j];
    }
    if (k0 + 64 < DM) {
#pragma unroll
      for (int j = 0; j < 4; ++j) {
        ar[j] = *reinterpret_cast<const bf16x8*>(ap + k0 + 64 + j * 8);
        br[j] = *reinterpret_cast<const bf16x8*>(bp + k0 + 64 + j * 8);
      }
    }
    __syncthreads();
#pragma unroll
    for (int kk = 0; kk < 2; ++kk) {
      bf16x8 af[4], bfv[4];
#pragma unroll
      for (int i = 0; i < 4; ++i) {
        af[i]  = *reinterpret_cast<const bf16x8*>(&At[wr + i * 16 + m][kk * 32 + q * 8]);
        bfv[i] = *reinterpret_cast<const bf16x8*>(&Bts[wc + i * 16 + m][kk * 32 + q * 8]);
      }
#pragma unroll
      for (int ai = 0; ai < 4; ++ai)
#pragma unroll
        for (int bi = 0; bi < 4; ++bi)
          acc[ai][bi] = MFMA16(af[ai], bfv[bi], acc[ai][bi]);
    }
  }
#pragma unroll
  for (int ai = 0; ai < 4; ++ai)
#pragma unroll
    for (int r2 = 0; r2 < 4; ++r2)
#pragma unroll
      for (int bi = 0; bi < 4; ++bi)
        C[(long)(m0 + wr + ai * 16 + q * 4 + r2) * QKVN + n0 + wc + bi * 16 + m] =
            (__bf16)acc[ai][bi][r2];
}

// ---------------------------------------------------------------------------
// K2: kf-features, SWAPPED operands + FRAGMENT-NATIVE kf output (validated).
// ---------------------------------------------------------------------------
__global__ __launch_bounds__(256) void features_mfma(const __bf16* __restrict__ qkv,
                                                     const __bf16* __restrict__ projB,
                                                     const __bf16* __restrict__ pi0,
                                                     const __bf16* __restrict__ pi1,
                                                     __bf16* __restrict__ kf) {
  const int l0 = blockIdx.x * 64;
  const int bh = blockIdx.y;
  const int h = bh & 7, b = bh >> 3;
  const int tid = threadIdx.x, lane = tid & 63, wv = tid >> 6;
  const int m = lane & 15, q = lane >> 4;
  __shared__ __bf16 As[2][64][72];   // k1 / k2 tiles: 64 l-rows x 64 d

  {
    const int r = tid >> 2, c0 = (tid & 3) * 16;
    const __bf16* ap = qkv + (long)((l0 + r) * B_SZ + b) * QKVN + h * 256 + 64 + c0;
#pragma unroll
    for (int t2 = 0; t2 < 2; ++t2) {
      *reinterpret_cast<bf16x8*>(&As[t2][r][c0]) =
          *reinterpret_cast<const bf16x8*>(ap + t2 * 64);
      *reinterpret_cast<bf16x8*>(&As[t2][r][c0 + 8]) =
          *reinterpret_cast<const bf16x8*>(ap + t2 * 64 + 8);
    }
  }
  const int l = l0 + wv * 16 + m;          // this thread's sequence row
  const float p0w = (float)pi0[h * 256 + l];
  const float p1w = (float)pi1[h * 256 + l];
  const float SQ = 0.35355339f;            // 64^-0.25
  const float SK2 = 0.24748737f;           // 0.7 * 64^-0.25
  __syncthreads();

  f32x4 acc1[16], acc2[16];
#pragma unroll
  for (int c = 0; c < 16; ++c) {
    acc1[c] = f32x4{0.f, 0.f, 0.f, 0.f};
    acc2[c] = f32x4{0.f, 0.f, 0.f, 0.f};
  }
#pragma unroll
  for (int kk = 0; kk < 2; ++kk) {
    const bf16x8 x1 = *reinterpret_cast<const bf16x8*>(&As[0][wv * 16 + m][kk * 32 + q * 8]);
    const bf16x8 x2 = *reinterpret_cast<const bf16x8*>(&As[1][wv * 16 + m][kk * 32 + q * 8]);
#pragma unroll
    for (int c = 0; c < 16; ++c) {
      const bf16x8 wf =
          *reinterpret_cast<const bf16x8*>(projB + (c * 2 + kk) * 512 + lane * 8);
      acc1[c] = MFMA16(wf, x1, acc1[c]);   // acc[c][r] = [l=wv*16+m][p=c*16+q*4+r]
      acc2[c] = MFMA16(wf, x2, acc2[c]);
    }
  }
  float mx1 = 0.f, mx2 = 0.f;
#pragma unroll
  for (int c = 0; c < 16; ++c)
#pragma unroll
    for (int r = 0; r < 4; ++r) {
      mx1 = fmaxf(mx1, fabsf(acc1[c][r] * SQ));
      mx2 = fmaxf(mx2, fabsf(acc2[c][r] * SK2));
    }
  mx1 = fmaxf(mx1, __shfl_xor(mx1, 16)); mx1 = fmaxf(mx1, __shfl_xor(mx1, 32));
  mx2 = fmaxf(mx2, __shfl_xor(mx2, 16)); mx2 = fmaxf(mx2, __shfl_xor(mx2, 32));
  const float C21 = __expf(-2.f * mx1);
  const float C22 = __expf(-2.f * mx2);
  float sm1 = 0.f, sm2 = 0.f;
#pragma unroll
  for (int c = 0; c < 16; ++c)
#pragma unroll
    for (int r = 0; r < 4; ++r) {
      const float e11 = __expf(acc1[c][r] * SQ - mx1);
      const float e12 = __expf(acc2[c][r] * SK2 - mx2);
      sm1 += e11 + C21 * __builtin_amdgcn_rcpf(e11);
      sm2 += e12 + C22 * __builtin_amdgcn_rcpf(e12);
      acc1[c][r] = e11;
      acc2[c][r] = e12;
    }
  sm1 += __shfl_xor(sm1, 16); sm1 += __shfl_xor(sm1, 32);
  sm2 += __shfl_xor(sm2, 16); sm2 += __shfl_xor(sm2, 32);
  const float w1 = p0w * __builtin_amdgcn_rcpf(sm1);
  const float w2 = p1w * __builtin_amdgcn_rcpf(sm2);
  const float K1 = C21 * w1, K2 = C22 * w2;
  // fragment-native store: chunk [lt = l>>4][c], lane offset = lane*8
  __bf16* op = kf + (((long)bh * 16 + (l >> 4)) * 16) * 512 + lane * 8;
#pragma unroll
  for (int c = 0; c < 16; ++c) {
    bf16x8 v;
#pragma unroll
    for (int r = 0; r < 4; ++r) {
      v[r]     = (__bf16)(w1 * acc1[c][r] + w2 * acc2[c][r]);
      v[4 + r] = (__bf16)(K1 * __builtin_amdgcn_rcpf(acc1[c][r]) +
                          K2 * __builtin_amdgcn_rcpf(acc2[c][r]));
    }
    *reinterpret_cast<bf16x8*>(op + c * 512) = v;
  }
}

// ---------------------------------------------------------------------------
// K2b: pack V into PV-fragment-native layout (validated round 12).
// ---------------------------------------------------------------------------
__global__ __launch_bounds__(256) void vpack(const __bf16* __restrict__ qkv,
                                             __bf16* __restrict__ vt) {
  const int st = blockIdx.x;
  const int s0 = st * 64;
  const int bh = blockIdx.y;
  const int h = bh & 7, b = bh >> 3;
  __shared__ __bf16 T[64][72];           // [d][s], row stride 144B (16B-mult)
  const int tid = threadIdx.x;
  {
    const int s = tid >> 2, d0 = (tid & 3) * 16;
    const __bf16* vp = qkv + ((long)((s0 + s) * B_SZ + b)) * QKVN + h * 256 + 192 + d0;
#pragma unroll
    for (int j = 0; j < 16; ++j) T[d0 + j][s] = vp[j];
  }
  __syncthreads();
  {
    const int lane = tid & 63, c2 = tid >> 6;
    const int m = lane & 15, q = lane >> 4;
    const int d = c2 * 16 + m;
#pragma unroll
    for (int kk = 0; kk < 2; ++kk) {
      const bf16x8 v = *reinterpret_cast<const bf16x8*>(&T[d][kk * 32 + q * 8]);
      *reinterpret_cast<bf16x8*>(vt + (((long)bh * 8 + st * 2 + kk) * 4 + c2) * 512 + lane * 8) = v;
    }
  }
}

// ---------------------------------------------------------------------------
// K3: flash (validated round 12): barrier-free + fragment-native coalesced
// loads; Pt transpose roundtrip wave-private LDS; id%8==bh%8 XCD locality.
// ---------------------------------------------------------------------------
__global__ __launch_bounds__(256, 3) void flash_mfma(const __bf16* __restrict__ qkv,
                                                     const __bf16* __restrict__ projB,
                                                     const __bf16* __restrict__ kf,
                                                     const __bf16* __restrict__ vt,
                                                     __bf16* __restrict__ att) {
  const int id = blockIdx.x;
  const int bh = id & 255;
  const int t  = ((id >> 8) + id) & 3;   // bijective per bh, mixed per round
  const int h = bh & 7, b = bh >> 3;
  const int tid = threadIdx.x, lane = tid & 63, wv = tid >> 6;
  const int m = lane & 15, q = lane >> 4;
  __shared__ __bf16 Pt[64][72];          // wave-private rows

  // ---------------- feature phase: qT[16] in-register ----------------
  const float SQ = 0.35355339f;          // 64^-0.25
  f32x4 acc[16];
#pragma unroll
  for (int c = 0; c < 16; ++c) acc[c] = f32x4{0.f, 0.f, 0.f, 0.f};
  const __bf16* xb = qkv + (long)((t * 64 + wv * 16 + m) * B_SZ + b) * QKVN + h * 256;
#pragma unroll
  for (int kk = 0; kk < 2; ++kk) {
    const bf16x8 xf = *reinterpret_cast<const bf16x8*>(xb + kk * 32 + q * 8);
#pragma unroll
    for (int c = 0; c < 16; ++c) {
      const bf16x8 wf =
          *reinterpret_cast<const bf16x8*>(projB + (c * 2 + kk) * 512 + lane * 8);
      acc[c] = MFMA16(wf, xf, acc[c]);   // acc[c][r] = qf-pre[l=wv*16+m][p=c*16+q*4+r]
    }
  }
  float mx = 0.f;
#pragma unroll
  for (int c = 0; c < 16; ++c)
#pragma unroll
    for (int r = 0; r < 4; ++r) mx = fmaxf(mx, fabsf(acc[c][r] * SQ));
  mx = fmaxf(mx, __shfl_xor(mx, 16));
  mx = fmaxf(mx, __shfl_xor(mx, 32));
  const float C2 = __expf(-2.f * mx);
  float sm = 0.f;
#pragma unroll
  for (int c = 0; c < 16; ++c)
#pragma unroll
    for (int r = 0; r < 4; ++r) {
      const float e1 = __expf(acc[c][r] * SQ - mx);
      sm += e1 + C2 * __builtin_amdgcn_rcpf(e1);
      acc[c][r] = e1;
    }
  sm += __shfl_xor(sm, 16);
  sm += __shfl_xor(sm, 32);
  const float inv = __builtin_amdgcn_rcpf(sm);
  const float K2 = C2 * inv;
  bf16x8 qT[16];                         // A-frags, k = q*8 + (r + 4*neg)
#pragma unroll
  for (int c = 0; c < 16; ++c) {
    bf16x8 v;
#pragma unroll
    for (int r = 0; r < 4; ++r) {
      v[r]     = (__bf16)(acc[c][r] * inv);
      v[4 + r] = (__bf16)(K2 * __builtin_amdgcn_rcpf(acc[c][r]));
    }
    qT[c] = v;
  }

  // ---------------- main loop: barrier-free, coalesced fragments ----------------
  f32x4 o[4];
#pragma unroll
  for (int i = 0; i < 4; ++i) o[i] = f32x4{0.f, 0.f, 0.f, 0.f};
  float den[4] = {0.f, 0.f, 0.f, 0.f};

  const __bf16* kfb = kf + (long)bh * (16 * 16 * 512) + lane * 8;
  const __bf16* vtb = vt + (long)bh * (8 * 4 * 512) + lane * 8;

  for (int st = 0; st <= t; ++st) {
    f32x4 s[4];
#pragma unroll
    for (int i = 0; i < 4; ++i) s[i] = f32x4{0.f, 0.f, 0.f, 0.f};
#pragma unroll
    for (int g = 0; g < 16; ++g) {
      const __bf16* kp = kfb + ((long)(st * 4) * 16 + g) * 512;
      const bf16x8 kb0 = *reinterpret_cast<const bf16x8*>(kp);
      const bf16x8 kb1 = *reinterpret_cast<const bf16x8*>(kp + 16 * 512);
      const bf16x8 kb2 = *reinterpret_cast<const bf16x8*>(kp + 32 * 512);
      const bf16x8 kb3 = *reinterpret_cast<const bf16x8*>(kp + 48 * 512);
      s[0] = MFMA16(qT[g], kb0, s[0]);
      s[1] = MFMA16(qT[g], kb1, s[1]);
      s[2] = MFMA16(qT[g], kb2, s[2]);
      s[3] = MFMA16(qT[g], kb3, s[3]);
    }
    // V fragments for this step (coalesced 1KB chunks)
    bf16x8 vf[8];
#pragma unroll
    for (int kk = 0; kk < 2; ++kk)
#pragma unroll
      for (int c = 0; c < 4; ++c)
        vf[kk * 4 + c] =
            *reinterpret_cast<const bf16x8*>(vtb + (((long)st * 2 + kk) * 4 + c) * 512);
    const bool last = (st == t);
#pragma unroll
    for (int c = 0; c < 4; ++c)
#pragma unroll
      for (int r = 0; r < 4; ++r) {
        const int row = wv * 16 + q * 4 + r, col = c * 16 + m;
        const float v = (last && col > row) ? 0.f : s[c][r];
        den[r] += v;
        Pt[row][col] = (__bf16)v;
      }
#pragma unroll
    for (int kk = 0; kk < 2; ++kk) {
      const bf16x8 pf = *reinterpret_cast<const bf16x8*>(&Pt[wv * 16 + m][kk * 32 + q * 8]);
#pragma unroll
      for (int c = 0; c < 4; ++c)
        o[c] = MFMA16(pf, vf[kk * 4 + c], o[c]);
    }
  }
#pragma unroll
  for (int r = 0; r < 4; ++r) {
    float d = den[r];
    d += __shfl_xor(d, 1); d += __shfl_xor(d, 2);
    d += __shfl_xor(d, 4); d += __shfl_xor(d, 8);
    const float invd = 0.125f / (d + 1e-5f);           // SCALE=64^-0.5, EPS
    const int row = t * 64 + wv * 16 + q * 4 + r;
#pragma unroll
    for (int c = 0; c < 4; ++c)
      att[((long)(row * B_SZ + b)) * DM + h * DH + c * 16 + m] = (__bf16)(o[c][r] * invd);
  }
}

// ---------------------------------------------------------------------------
// K4: xrow = hb + att @ w_o (f32 out), round 13: 128x128 tile (same structure
// as K1), per-wave 64x64, BK=64.
// ---------------------------------------------------------------------------
__global__ __launch_bounds__(256) void gemm_att_wo(const __bf16* __restrict__ A,
                                                   const __bf16* __restrict__ Bt,
                                                   const __bf16* __restrict__ hb,
                                                   float* __restrict__ xrow) {
  __shared__ __bf16 At[128][72];
  __shared__ __bf16 Bts[128][72];
  const int n0 = blockIdx.x * 128, m0 = blockIdx.y * 128;
  const int tid = threadIdx.x, lane = tid & 63, wv = tid >> 6;
  const int m = lane & 15, q = lane >> 4;
  const int wr = (wv >> 1) * 64, wc = (wv & 1) * 64;
  const int r = tid >> 1, c0 = (tid & 1) * 32;
  const __bf16* ap = A + (long)(m0 + r) * DM + c0;
  const __bf16* bp = Bt + (long)(n0 + r) * DM + c0;
  f32x4 acc[4][4];
#pragma unroll
  for (int i = 0; i < 4; ++i)
#pragma unroll
    for (int j = 0; j < 4; ++j) acc[i][j] = f32x4{0.f, 0.f, 0.f, 0.f};

  bf16x8 ar[4], br[4];
#pragma unroll
  for (int j = 0; j < 4; ++j) {
    ar[j] = *reinterpret_cast<const bf16x8*>(ap + j * 8);
    br[j] = *reinterpret_cast<const bf16x8*>(bp + j * 8);
  }
  for (int k0 = 0; k0 < DM; k0 += 64) {
    __syncthreads();
#pragma unroll
    for (int j = 0; j < 4; ++j) {
      *reinterpret_cast<bf16x8*>(&At[r][c0 + j * 8]) = ar[j];
      *reinterpret_cast<bf16x8*>(&Bts[r][c0 + j * 8]) = br[j];
    }
    if (k0 + 64 < DM) {
#pragma unroll
      for (int j = 0; j < 4; ++j) {
        ar[j] = *reinterpret_cast<const bf16x8*>(ap + k0 + 64 + j * 8);
        br[j] = *reinterpret_cast<const bf16x8*>(bp + k0 + 64 + j * 8);
      }
    }
    __syncthreads();
#pragma unroll
    for (int kk = 0; kk < 2; ++kk) {
      bf16x8 af[4], bfv[4];
#pragma unroll
      for (int i = 0; i < 4; ++i) {
        af[i]  = *reinterpret_cast<const bf16x8*>(&At[wr + i * 16 + m][kk * 32 + q * 8]);
        bfv[i] = *reinterpret_cast<const bf16x8*>(&Bts[wc + i * 16 + m][kk * 32 + q * 8]);
      }
#pragma unroll
      for (int ai = 0; ai < 4; ++ai)
#pragma unroll
        for (int bi = 0; bi < 4; ++bi)
          acc[ai][bi] = MFMA16(af[ai], bfv[bi], acc[ai][bi]);
    }
  }
#pragma unroll
  for (int ai = 0; ai < 4; ++ai)
#pragma unroll
    for (int r2 = 0; r2 < 4; ++r2)
#pragma unroll
      for (int bi = 0; bi < 4; ++bi) {
        const long row = m0 + wr + ai * 16 + q * 4 + r2;
        const long col = n0 + wc + bi * 16 + m;
        xrow[row * DM + col] = acc[ai][bi][r2] + (float)hb[row * DM + col];
      }
}

// ---------------------------------------------------------------------------
// K5: LayerNorm rows of xrow -> out (validated rounds 4-8).
// ---------------------------------------------------------------------------
__global__ __launch_bounds__(256) void ln_out(const float* __restrict__ xrow,
                                              const __bf16* __restrict__ gamma,
                                              const __bf16* __restrict__ beta,
                                              const int* __restrict__ flag,
                                              void* __restrict__ out) {
  const int f32 = flag[0];
  const int r = blockIdx.x;
  const int tid = threadIdx.x;
  __shared__ float red[256];
  const float x0 = xrow[(long)r * DM + tid];
  const float x1 = xrow[(long)r * DM + tid + 256];

  red[tid] = x0 + x1; __syncthreads();
  for (int s = 128; s > 0; s >>= 1) { if (tid < s) red[tid] += red[tid + s]; __syncthreads(); }
  const float mu = red[0] * (1.f / 512.f); __syncthreads();
  red[tid] = x0 * x0 + x1 * x1; __syncthreads();
  for (int s = 128; s > 0; s >>= 1) { if (tid < s) red[tid] += red[tid + s]; __syncthreads(); }
  const float var = red[0] * (1.f / 512.f) - mu * mu; __syncthreads();
  const float rstd = rsqrtf(var + 1e-5f);

  stmix(out, (long)r * DM + tid,
        (x0 - mu) * rstd * (float)gamma[tid] + (float)beta[tid], f32);
  stmix(out, (long)r * DM + tid + 256,
        (x1 - mu) * rstd * (float)gamma[tid + 256] + (float)beta[tid + 256], f32);
}

// ---------------------------------------------------------------------------
extern "C" void kernel_launch(void* const* d_in, const int* in_sizes, int n_in,
                              void* d_out, int out_size, void* d_ws, size_t ws_size,
                              hipStream_t stream) {
  (void)in_sizes; (void)n_in; (void)out_size; (void)ws_size;
  char* ws = (char*)d_ws;
  __bf16* qkv   = (__bf16*)ws;
  int*    flag  = (int*)(ws + 33554432);
  __bf16* wt    = (__bf16*)(ws + 33554688);
  __bf16* wot   = (__bf16*)(ws + 35651840);
  __bf16* att   = (__bf16*)(ws + 36176128);
  __bf16* vt    = (__bf16*)(ws + 44564736);
  __bf16* hb    = (__bf16*)(ws + 52953344);
  __bf16* projT = (__bf16*)(ws + 61341952);
  __bf16* pi0b  = (__bf16*)(ws + 61374720);
  __bf16* pi1b  = (__bf16*)(ws + 61378816);
  __bf16* gamb  = (__bf16*)(ws + 61382912);
  __bf16* betb  = (__bf16*)(ws + 61383936);
  float*  xrow  = (float*)(ws + 61384960);   // 16 MB
  __bf16* projB = (__bf16*)(ws + 78163968);  // 32 KB fragment-native proj
  __bf16* kf    = (__bf16*)(ws + 128493824);

  prep<<<PREP_BLOCKS, 256, 0, stream>>>(d_in[0], d_in[1], d_in[2], d_in[7],
                                        d_in[5], d_in[6], d_in[3], d_in[4],
                                        flag, hb, wt, wot, projT,
                                        pi0b, pi1b, gamb, betb, projB);
  gemm_h_wqkv<<<dim3(16, 64), 256, 0, stream>>>(hb, wt, qkv);
  vpack<<<dim3(4, 256), 256, 0, stream>>>(qkv, vt);
  features_mfma<<<dim3(4, 256), 256, 0, stream>>>(qkv, projB, pi0b, pi1b, kf);
  flash_mfma<<<dim3(1024), 256, 0, stream>>>(qkv, projB, kf, vt, att);
  gemm_att_wo<<<dim3(4, 64), 256, 0, stream>>>(att, wot, hb, xrow);
  ln_out<<<dim3(ROWS), 256, 0, stream>>>(xrow, gamb, betb, flag, d_out);
}

// Round 6
// 219.931 us; speedup vs baseline: 1.3354x; 1.0183x over previous
//
#include <hip/hip_runtime.h>
#include <hip/hip_bf16.h>

// L=256, B=32, H=8, d_head=64, m=256, feature dim 2m=512, D_MODEL=512
#define L_SEQ 256
#define B_SZ  32
#define NH    8
#define DH    64
#define DM    512
#define FD    512
#define PM    256
#define ROWS  8192
#define QKVN  2048

typedef __bf16 bf16x8 __attribute__((ext_vector_type(8)));
typedef float f32x4 __attribute__((ext_vector_type(4)));
#define MFMA16(a, b, c) __builtin_amdgcn_mfma_f32_16x16x32_bf16((a), (b), (c), 0, 0, 0)

static __device__ __forceinline__ void stmix(void* p, long i, float v, int f32) {
  if (f32) ((float*)p)[i] = v;
  else     ((__bf16*)p)[i] = (__bf16)v;
}

// ---------------------------------------------------------------------------
// P0: prep — probe + h-cvt + 3 transposes + tiny cvts + projB fragment pack.
// projB layout (fragment-native): chunk (c,kk) at lane=q*16+m, elem e holds
// projT[p = c*16+m][d = kk*32+q*8+e] = proj[d][p] = T[kk*32+q*8+e][p-n0].
// ---------------------------------------------------------------------------
#define PREP_HB   2048
#define PREP_WT   256
#define PREP_WOT  64
#define PREP_PJ   4
#define PREP_TINY 1
#define PREP_BLOCKS (PREP_HB + PREP_WT + PREP_WOT + PREP_PJ + PREP_TINY)

__global__ __launch_bounds__(256) void prep(
    const void* __restrict__ h, const void* __restrict__ wqkv,
    const void* __restrict__ wo, const void* __restrict__ proj,
    const void* __restrict__ pi0, const void* __restrict__ pi1,
    const void* __restrict__ gam, const void* __restrict__ bet,
    int* __restrict__ flag, __bf16* __restrict__ hb, __bf16* __restrict__ wt,
    __bf16* __restrict__ wot, __bf16* __restrict__ projT,
    __bf16* __restrict__ pi0b, __bf16* __restrict__ pi1b,
    __bf16* __restrict__ gamb, __bf16* __restrict__ betb,
    __bf16* __restrict__ projB) {
  __shared__ float T[64][69];
  __shared__ int red[256];
  const int tid = threadIdx.x;
  int cnt = 0;
  {
    const unsigned short* hbits = (const unsigned short*)h;
    for (int i = 0; i < 16; ++i) {
      const unsigned short u = hbits[tid * 16 + i];
      if (((u >> 7) & 0xFF) >= 0xA0) ++cnt;
    }
  }
  red[tid] = cnt; __syncthreads();
  for (int s = 128; s > 0; s >>= 1) { if (tid < s) red[tid] += red[tid + s]; __syncthreads(); }
  const int f32 = (red[0] >= 64) ? 1 : 0;
  __syncthreads();

  const int blk = blockIdx.x;
  if (blk < PREP_HB) {
    const int i = blk * 256 + tid;
    if (f32) {
      const f32x4* s = (const f32x4*)h;
      const f32x4 a = s[i * 2], b = s[i * 2 + 1];
      bf16x8 t;
      t[0] = (__bf16)a[0]; t[1] = (__bf16)a[1]; t[2] = (__bf16)a[2]; t[3] = (__bf16)a[3];
      t[4] = (__bf16)b[0]; t[5] = (__bf16)b[1]; t[6] = (__bf16)b[2]; t[7] = (__bf16)b[3];
      *reinterpret_cast<bf16x8*>(hb + (long)i * 8) = t;
    } else {
      *reinterpret_cast<bf16x8*>(hb + (long)i * 8) = ((const bf16x8*)h)[i];
    }
    return;
  }
  const void* src; __bf16* dst; int M, N, n0, m0;
  int pjx = -1;
  if (blk < PREP_HB + PREP_WT) {
    const int x = blk - PREP_HB;
    src = wqkv; dst = wt; M = 512; N = 2048; n0 = (x & 31) * 64; m0 = (x >> 5) * 64;
  } else if (blk < PREP_HB + PREP_WT + PREP_WOT) {
    const int x = blk - PREP_HB - PREP_WT;
    src = wo; dst = wot; M = 512; N = 512; n0 = (x & 7) * 64; m0 = (x >> 3) * 64;
  } else if (blk < PREP_HB + PREP_WT + PREP_WOT + PREP_PJ) {
    const int x = blk - PREP_HB - PREP_WT - PREP_WOT;
    src = proj; dst = projT; M = 64; N = 256; n0 = x * 64; m0 = 0;
    pjx = x;
  } else {
    if (tid == 0) flag[0] = f32;
    if (f32) {
      const float* s0 = (const float*)pi0; const float* s1 = (const float*)pi1;
      const float* s2 = (const float*)gam; const float* s3 = (const float*)bet;
      for (int i = tid; i < NH * 256; i += 256) { pi0b[i] = (__bf16)s0[i]; pi1b[i] = (__bf16)s1[i]; }
      for (int i = tid; i < DM; i += 256)      { gamb[i] = (__bf16)s2[i]; betb[i] = (__bf16)s3[i]; }
    } else {
      const __bf16* s0 = (const __bf16*)pi0; const __bf16* s1 = (const __bf16*)pi1;
      const __bf16* s2 = (const __bf16*)gam; const __bf16* s3 = (const __bf16*)bet;
      for (int i = tid; i < NH * 256; i += 256) { pi0b[i] = s0[i]; pi1b[i] = s1[i]; }
      for (int i = tid; i < DM; i += 256)      { gamb[i] = s2[i]; betb[i] = s3[i]; }
    }
    return;
  }
  if (f32) {
    const float* s = (const float*)src;
#pragma unroll
    for (int rep = 0; rep < 16; ++rep) {
      const int i = rep * 4 + (tid >> 6), j = tid & 63;
      T[i][j] = s[(long)(m0 + i) * N + n0 + j];
    }
  } else {
    const __bf16* s = (const __bf16*)src;
#pragma unroll
    for (int rep = 0; rep < 16; ++rep) {
      const int i = rep * 4 + (tid >> 6), j = tid & 63;
      T[i][j] = (float)s[(long)(m0 + i) * N + n0 + j];
    }
  }
  __syncthreads();
#pragma unroll
  for (int rep = 0; rep < 16; ++rep) {
    const int i = rep * 4 + (tid >> 6), j = tid & 63;
    dst[(long)(n0 + i) * M + m0 + j] = (__bf16)T[j][i];
  }
  if (pjx >= 0) {
    // fragment-native pack. T[d][p-n0] here (rows = d, cols = feature):
    // chunk c=pjx*4+sub, lane (m,q), elem e := proj[d = kk*32+q*8+e][p = c*16+m]
    const int lane = tid & 63, sub = tid >> 6;
    const int mm = lane & 15, qq = lane >> 4;
#pragma unroll
    for (int kk2 = 0; kk2 < 2; ++kk2) {
      bf16x8 v;
#pragma unroll
      for (int e = 0; e < 8; ++e) v[e] = (__bf16)T[kk2 * 32 + qq * 8 + e][sub * 16 + mm];
      *reinterpret_cast<bf16x8*>(projB + ((pjx * 4 + sub) * 2 + kk2) * 512 + lane * 8) = v;
    }
  }
}

// ---------------------------------------------------------------------------
// K1: qkv = hb @ w_qkv, 128x128 tile, BK=64, per-wave 64x64 (validated r13).
// ---------------------------------------------------------------------------
__global__ __launch_bounds__(256) void gemm_h_wqkv(const __bf16* __restrict__ A,
                                                   const __bf16* __restrict__ Bt,
                                                   __bf16* __restrict__ C) {
  __shared__ __bf16 At[128][72];
  __shared__ __bf16 Bts[128][72];
  const int n0 = blockIdx.x * 128, m0 = blockIdx.y * 128;
  const int tid = threadIdx.x, lane = tid & 63, wv = tid >> 6;
  const int m = lane & 15, q = lane >> 4;
  const int wr = (wv >> 1) * 64, wc = (wv & 1) * 64;
  const int r = tid >> 1, c0 = (tid & 1) * 32;
  const __bf16* ap = A + (long)(m0 + r) * DM + c0;
  const __bf16* bp = Bt + (long)(n0 + r) * DM + c0;
  f32x4 acc[4][4];
#pragma unroll
  for (int i = 0; i < 4; ++i)
#pragma unroll
    for (int j = 0; j < 4; ++j) acc[i][j] = f32x4{0.f, 0.f, 0.f, 0.f};

  bf16x8 ar[4], br[4];
#pragma unroll
  for (int j = 0; j < 4; ++j) {
    ar[j] = *reinterpret_cast<const bf16x8*>(ap + j * 8);
    br[j] = *reinterpret_cast<const bf16x8*>(bp + j * 8);
  }
  for (int k0 = 0; k0 < DM; k0 += 64) {
    __syncthreads();
#pragma unroll
    for (int j = 0; j < 4; ++j) {
      *reinterpret_cast<bf16x8*>(&At[r][c0 + j * 8]) = ar[j];
      *reinterpret_cast<bf16x8*>(&Bts[r][c0 + j * 8]) = br[j];
    }
    if (k0 + 64 < DM) {
#pragma unroll
      for (int j = 0; j < 4; ++j) {
        ar[j] = *reinterpret_cast<const bf16x8*>(ap + k0 + 64 + j * 8);
        br[j] = *reinterpret_cast<const bf16x8*>(bp + k0 + 64 + j * 8);
      }
    }
    __syncthreads();
#pragma unroll
    for (int kk = 0; kk < 2; ++kk) {
      bf16x8 af[4], bfv[4];
#pragma unroll
      for (int i = 0; i < 4; ++i) {
        af[i]  = *reinterpret_cast<const bf16x8*>(&At[wr + i * 16 + m][kk * 32 + q * 8]);
        bfv[i] = *reinterpret_cast<const bf16x8*>(&Bts[wc + i * 16 + m][kk * 32 + q * 8]);
      }
#pragma unroll
      for (int ai = 0; ai < 4; ++ai)
#pragma unroll
        for (int bi = 0; bi < 4; ++bi)
          acc[ai][bi] = MFMA16(af[ai], bfv[bi], acc[ai][bi]);
    }
  }
#pragma unroll
  for (int ai = 0; ai < 4; ++ai)
#pragma unroll
    for (int r2 = 0; r2 < 4; ++r2)
#pragma unroll
      for (int bi = 0; bi < 4; ++bi)
        C[(long)(m0 + wr + ai * 16 + q * 4 + r2) * QKVN + n0 + wc + bi * 16 + m] =
            (__bf16)acc[ai][bi][r2];
}

// ---------------------------------------------------------------------------
// K2: kf-features, SWAPPED operands + FRAGMENT-NATIVE kf output (validated).
// ---------------------------------------------------------------------------
__global__ __launch_bounds__(256) void features_mfma(const __bf16* __restrict__ qkv,
                                                     const __bf16* __restrict__ projB,
                                                     const __bf16* __restrict__ pi0,
                                                     const __bf16* __restrict__ pi1,
                                                     __bf16* __restrict__ kf) {
  const int l0 = blockIdx.x * 64;
  const int bh = blockIdx.y;
  const int h = bh & 7, b = bh >> 3;
  const int tid = threadIdx.x, lane = tid & 63, wv = tid >> 6;
  const int m = lane & 15, q = lane >> 4;
  __shared__ __bf16 As[2][64][72];   // k1 / k2 tiles: 64 l-rows x 64 d

  {
    const int r = tid >> 2, c0 = (tid & 3) * 16;
    const __bf16* ap = qkv + (long)((l0 + r) * B_SZ + b) * QKVN + h * 256 + 64 + c0;
#pragma unroll
    for (int t2 = 0; t2 < 2; ++t2) {
      *reinterpret_cast<bf16x8*>(&As[t2][r][c0]) =
          *reinterpret_cast<const bf16x8*>(ap + t2 * 64);
      *reinterpret_cast<bf16x8*>(&As[t2][r][c0 + 8]) =
          *reinterpret_cast<const bf16x8*>(ap + t2 * 64 + 8);
    }
  }
  const int l = l0 + wv * 16 + m;          // this thread's sequence row
  const float p0w = (float)pi0[h * 256 + l];
  const float p1w = (float)pi1[h * 256 + l];
  const float SQ = 0.35355339f;            // 64^-0.25
  const float SK2 = 0.24748737f;           // 0.7 * 64^-0.25
  __syncthreads();

  f32x4 acc1[16], acc2[16];
#pragma unroll
  for (int c = 0; c < 16; ++c) {
    acc1[c] = f32x4{0.f, 0.f, 0.f, 0.f};
    acc2[c] = f32x4{0.f, 0.f, 0.f, 0.f};
  }
#pragma unroll
  for (int kk = 0; kk < 2; ++kk) {
    const bf16x8 x1 = *reinterpret_cast<const bf16x8*>(&As[0][wv * 16 + m][kk * 32 + q * 8]);
    const bf16x8 x2 = *reinterpret_cast<const bf16x8*>(&As[1][wv * 16 + m][kk * 32 + q * 8]);
#pragma unroll
    for (int c = 0; c < 16; ++c) {
      const bf16x8 wf =
          *reinterpret_cast<const bf16x8*>(projB + (c * 2 + kk) * 512 + lane * 8);
      acc1[c] = MFMA16(wf, x1, acc1[c]);   // acc[c][r] = [l=wv*16+m][p=c*16+q*4+r]
      acc2[c] = MFMA16(wf, x2, acc2[c]);
    }
  }
  float mx1 = 0.f, mx2 = 0.f;
#pragma unroll
  for (int c = 0; c < 16; ++c)
#pragma unroll
    for (int r = 0; r < 4; ++r) {
      mx1 = fmaxf(mx1, fabsf(acc1[c][r] * SQ));
      mx2 = fmaxf(mx2, fabsf(acc2[c][r] * SK2));
    }
  mx1 = fmaxf(mx1, __shfl_xor(mx1, 16)); mx1 = fmaxf(mx1, __shfl_xor(mx1, 32));
  mx2 = fmaxf(mx2, __shfl_xor(mx2, 16)); mx2 = fmaxf(mx2, __shfl_xor(mx2, 32));
  const float C21 = __expf(-2.f * mx1);
  const float C22 = __expf(-2.f * mx2);
  float sm1 = 0.f, sm2 = 0.f;
#pragma unroll
  for (int c = 0; c < 16; ++c)
#pragma unroll
    for (int r = 0; r < 4; ++r) {
      const float e11 = __expf(acc1[c][r] * SQ - mx1);
      const float e12 = __expf(acc2[c][r] * SK2 - mx2);
      sm1 += e11 + C21 * __builtin_amdgcn_rcpf(e11);
      sm2 += e12 + C22 * __builtin_amdgcn_rcpf(e12);
      acc1[c][r] = e11;
      acc2[c][r] = e12;
    }
  sm1 += __shfl_xor(sm1, 16); sm1 += __shfl_xor(sm1, 32);
  sm2 += __shfl_xor(sm2, 16); sm2 += __shfl_xor(sm2, 32);
  const float w1 = p0w * __builtin_amdgcn_rcpf(sm1);
  const float w2 = p1w * __builtin_amdgcn_rcpf(sm2);
  const float K1 = C21 * w1, K2 = C22 * w2;
  // fragment-native store: chunk [lt = l>>4][c], lane offset = lane*8
  __bf16* op = kf + (((long)bh * 16 + (l >> 4)) * 16) * 512 + lane * 8;
#pragma unroll
  for (int c = 0; c < 16; ++c) {
    bf16x8 v;
#pragma unroll
    for (int r = 0; r < 4; ++r) {
      v[r]     = (__bf16)(w1 * acc1[c][r] + w2 * acc2[c][r]);
      v[4 + r] = (__bf16)(K1 * __builtin_amdgcn_rcpf(acc1[c][r]) +
                          K2 * __builtin_amdgcn_rcpf(acc2[c][r]));
    }
    *reinterpret_cast<bf16x8*>(op + c * 512) = v;
  }
}

// ---------------------------------------------------------------------------
// K2b: pack V into PV-fragment-native layout (validated round 12).
// ---------------------------------------------------------------------------
__global__ __launch_bounds__(256) void vpack(const __bf16* __restrict__ qkv,
                                             __bf16* __restrict__ vt) {
  const int st = blockIdx.x;
  const int s0 = st * 64;
  const int bh = blockIdx.y;
  const int h = bh & 7, b = bh >> 3;
  __shared__ __bf16 T[64][72];           // [d][s], row stride 144B (16B-mult)
  const int tid = threadIdx.x;
  {
    const int s = tid >> 2, d0 = (tid & 3) * 16;
    const __bf16* vp = qkv + ((long)((s0 + s) * B_SZ + b)) * QKVN + h * 256 + 192 + d0;
#pragma unroll
    for (int j = 0; j < 16; ++j) T[d0 + j][s] = vp[j];
  }
  __syncthreads();
  {
    const int lane = tid & 63, c2 = tid >> 6;
    const int m = lane & 15, q = lane >> 4;
    const int d = c2 * 16 + m;
#pragma unroll
    for (int kk = 0; kk < 2; ++kk) {
      const bf16x8 v = *reinterpret_cast<const bf16x8*>(&T[d][kk * 32 + q * 8]);
      *reinterpret_cast<bf16x8*>(vt + (((long)bh * 8 + st * 2 + kk) * 4 + c2) * 512 + lane * 8) = v;
    }
  }
}

// ---------------------------------------------------------------------------
// K3: flash, round 14: TWO A-frags per wave (32 q-rows) — each loaded kf/V
// chunk feeds 2 MFMAs (VMEM instrs per output row halved vs round 13).
// 128-thread blocks (2 waves per 64-row tile), barrier-free, fragment-native
// coalesced loads, wave-private Pt rows, id%8==bh%8 XCD locality.
// ---------------------------------------------------------------------------
__global__ __launch_bounds__(128, 2) void flash_mfma(const __bf16* __restrict__ qkv,
                                                     const __bf16* __restrict__ projB,
                                                     const __bf16* __restrict__ kf,
                                                     const __bf16* __restrict__ vt,
                                                     __bf16* __restrict__ att) {
  const int id = blockIdx.x;
  const int bh = id & 255;
  const int t  = ((id >> 8) + id) & 3;   // bijective per bh, mixed per round
  const int h = bh & 7, b = bh >> 3;
  const int tid = threadIdx.x, lane = tid & 63, w = tid >> 6;
  const int m = lane & 15, q = lane >> 4;
  __shared__ __bf16 Pt[64][72];          // wave w owns rows [32w, 32w+32)

  // ---------------- feature phase: qT0/qT1 in-register ----------------
  const float SQ = 0.35355339f;          // 64^-0.25
  bf16x8 qT0[16], qT1[16];               // A-frags, k = q*8 + (r + 4*neg)
#pragma unroll
  for (int j = 0; j < 2; ++j) {
    f32x4 acc[16];
#pragma unroll
    for (int c = 0; c < 16; ++c) acc[c] = f32x4{0.f, 0.f, 0.f, 0.f};
    const __bf16* xb =
        qkv + (long)((t * 64 + w * 32 + j * 16 + m) * B_SZ + b) * QKVN + h * 256;
#pragma unroll
    for (int kk = 0; kk < 2; ++kk) {
      const bf16x8 xf = *reinterpret_cast<const bf16x8*>(xb + kk * 32 + q * 8);
#pragma unroll
      for (int c = 0; c < 16; ++c) {
        const bf16x8 wf =
            *reinterpret_cast<const bf16x8*>(projB + (c * 2 + kk) * 512 + lane * 8);
        acc[c] = MFMA16(wf, xf, acc[c]);
      }
    }
    float mx = 0.f;
#pragma unroll
    for (int c = 0; c < 16; ++c)
#pragma unroll
      for (int r = 0; r < 4; ++r) mx = fmaxf(mx, fabsf(acc[c][r] * SQ));
    mx = fmaxf(mx, __shfl_xor(mx, 16));
    mx = fmaxf(mx, __shfl_xor(mx, 32));
    const float C2 = __expf(-2.f * mx);
    float sm = 0.f;
#pragma unroll
    for (int c = 0; c < 16; ++c)
#pragma unroll
      for (int r = 0; r < 4; ++r) {
        const float e1 = __expf(acc[c][r] * SQ - mx);
        sm += e1 + C2 * __builtin_amdgcn_rcpf(e1);
        acc[c][r] = e1;
      }
    sm += __shfl_xor(sm, 16);
    sm += __shfl_xor(sm, 32);
    const float inv = __builtin_amdgcn_rcpf(sm);
    const float K2 = C2 * inv;
    bf16x8* qT = j ? qT1 : qT0;
#pragma unroll
    for (int c = 0; c < 16; ++c) {
      bf16x8 v;
#pragma unroll
      for (int r = 0; r < 4; ++r) {
        v[r]     = (__bf16)(acc[c][r] * inv);
        v[4 + r] = (__bf16)(K2 * __builtin_amdgcn_rcpf(acc[c][r]));
      }
      qT[c] = v;
    }
  }

  // ---------------- main loop: barrier-free, 2 MFMAs per loaded chunk ----------------
  f32x4 o0[4], o1[4];
#pragma unroll
  for (int i = 0; i < 4; ++i) { o0[i] = f32x4{0.f, 0.f, 0.f, 0.f}; o1[i] = o0[i]; }
  float den0[4] = {0.f, 0.f, 0.f, 0.f}, den1[4] = {0.f, 0.f, 0.f, 0.f};

  const __bf16* kfb = kf + (long)bh * (16 * 16 * 512) + lane * 8;
  const __bf16* vtb = vt + (long)bh * (8 * 4 * 512) + lane * 8;

  for (int st = 0; st <= t; ++st) {
    f32x4 s0[4], s1[4];
#pragma unroll
    for (int i = 0; i < 4; ++i) { s0[i] = f32x4{0.f, 0.f, 0.f, 0.f}; s1[i] = s0[i]; }
#pragma unroll
    for (int g = 0; g < 16; ++g) {
      const __bf16* kp = kfb + ((long)(st * 4) * 16 + g) * 512;
      const bf16x8 kb0 = *reinterpret_cast<const bf16x8*>(kp);
      const bf16x8 kb1 = *reinterpret_cast<const bf16x8*>(kp + 16 * 512);
      const bf16x8 kb2 = *reinterpret_cast<const bf16x8*>(kp + 32 * 512);
      const bf16x8 kb3 = *reinterpret_cast<const bf16x8*>(kp + 48 * 512);
      s0[0] = MFMA16(qT0[g], kb0, s0[0]);  s1[0] = MFMA16(qT1[g], kb0, s1[0]);
      s0[1] = MFMA16(qT0[g], kb1, s0[1]);  s1[1] = MFMA16(qT1[g], kb1, s1[1]);
      s0[2] = MFMA16(qT0[g], kb2, s0[2]);  s1[2] = MFMA16(qT1[g], kb2, s1[2]);
      s0[3] = MFMA16(qT0[g], kb3, s0[3]);  s1[3] = MFMA16(qT1[g], kb3, s1[3]);
    }
    const bool last = (st == t);
    // P stage: frag 0 rows [32w,32w+16), frag 1 rows [32w+16,32w+32)
#pragma unroll
    for (int c = 0; c < 4; ++c)
#pragma unroll
      for (int r = 0; r < 4; ++r) {
        const int col = c * 16 + m;
        const int row0 = w * 32 + q * 4 + r;
        const float v0 = (last && col > row0) ? 0.f : s0[c][r];
        den0[r] += v0;
        Pt[row0][col] = (__bf16)v0;
        const int row1 = row0 + 16;
        const float v1 = (last && col > row1) ? 0.f : s1[c][r];
        den1[r] += v1;
        Pt[row1][col] = (__bf16)v1;
      }
#pragma unroll
    for (int kk = 0; kk < 2; ++kk) {
      bf16x8 vf[4];
#pragma unroll
      for (int c = 0; c < 4; ++c)
        vf[c] = *reinterpret_cast<const bf16x8*>(vtb + (((long)st * 2 + kk) * 4 + c) * 512);
      const bf16x8 pf0 = *reinterpret_cast<const bf16x8*>(&Pt[w * 32 + m][kk * 32 + q * 8]);
      const bf16x8 pf1 = *reinterpret_cast<const bf16x8*>(&Pt[w * 32 + 16 + m][kk * 32 + q * 8]);
#pragma unroll
      for (int c = 0; c < 4; ++c) {
        o0[c] = MFMA16(pf0, vf[c], o0[c]);
        o1[c] = MFMA16(pf1, vf[c], o1[c]);
      }
    }
  }
#pragma unroll
  for (int j = 0; j < 2; ++j) {
    const float* den = j ? den1 : den0;
    const f32x4* o = j ? o1 : o0;
#pragma unroll
    for (int r = 0; r < 4; ++r) {
      float d = den[r];
      d += __shfl_xor(d, 1); d += __shfl_xor(d, 2);
      d += __shfl_xor(d, 4); d += __shfl_xor(d, 8);
      const float invd = 0.125f / (d + 1e-5f);         // SCALE=64^-0.5, EPS
      const int row = t * 64 + w * 32 + j * 16 + q * 4 + r;
#pragma unroll
      for (int c = 0; c < 4; ++c)
        att[((long)(row * B_SZ + b)) * DM + h * DH + c * 16 + m] = (__bf16)(o[c][r] * invd);
    }
  }
}

// ---------------------------------------------------------------------------
// K4: xrow = hb + att @ w_o (f32 out), 128x128 tile (validated r13).
// ---------------------------------------------------------------------------
__global__ __launch_bounds__(256) void gemm_att_wo(const __bf16* __restrict__ A,
                                                   const __bf16* __restrict__ Bt,
                                                   const __bf16* __restrict__ hb,
                                                   float* __restrict__ xrow) {
  __shared__ __bf16 At[128][72];
  __shared__ __bf16 Bts[128][72];
  const int n0 = blockIdx.x * 128, m0 = blockIdx.y * 128;
  const int tid = threadIdx.x, lane = tid & 63, wv = tid >> 6;
  const int m = lane & 15, q = lane >> 4;
  const int wr = (wv >> 1) * 64, wc = (wv & 1) * 64;
  const int r = tid >> 1, c0 = (tid & 1) * 32;
  const __bf16* ap = A + (long)(m0 + r) * DM + c0;
  const __bf16* bp = Bt + (long)(n0 + r) * DM + c0;
  f32x4 acc[4][4];
#pragma unroll
  for (int i = 0; i < 4; ++i)
#pragma unroll
    for (int j = 0; j < 4; ++j) acc[i][j] = f32x4{0.f, 0.f, 0.f, 0.f};

  bf16x8 ar[4], br[4];
#pragma unroll
  for (int j = 0; j < 4; ++j) {
    ar[j] = *reinterpret_cast<const bf16x8*>(ap + j * 8);
    br[j] = *reinterpret_cast<const bf16x8*>(bp + j * 8);
  }
  for (int k0 = 0; k0 < DM; k0 += 64) {
    __syncthreads();
#pragma unroll
    for (int j = 0; j < 4; ++j) {
      *reinterpret_cast<bf16x8*>(&At[r][c0 + j * 8]) = ar[j];
      *reinterpret_cast<bf16x8*>(&Bts[r][c0 + j * 8]) = br[j];
    }
    if (k0 + 64 < DM) {
#pragma unroll
      for (int j = 0; j < 4; ++j) {
        ar[j] = *reinterpret_cast<const bf16x8*>(ap + k0 + 64 + j * 8);
        br[j] = *reinterpret_cast<const bf16x8*>(bp + k0 + 64 + j * 8);
      }
    }
    __syncthreads();
#pragma unroll
    for (int kk = 0; kk < 2; ++kk) {
      bf16x8 af[4], bfv[4];
#pragma unroll
      for (int i = 0; i < 4; ++i) {
        af[i]  = *reinterpret_cast<const bf16x8*>(&At[wr + i * 16 + m][kk * 32 + q * 8]);
        bfv[i] = *reinterpret_cast<const bf16x8*>(&Bts[wc + i * 16 + m][kk * 32 + q * 8]);
      }
#pragma unroll
      for (int ai = 0; ai < 4; ++ai)
#pragma unroll
        for (int bi = 0; bi < 4; ++bi)
          acc[ai][bi] = MFMA16(af[ai], bfv[bi], acc[ai][bi]);
    }
  }
#pragma unroll
  for (int ai = 0; ai < 4; ++ai)
#pragma unroll
    for (int r2 = 0; r2 < 4; ++r2)
#pragma unroll
      for (int bi = 0; bi < 4; ++bi) {
        const long row = m0 + wr + ai * 16 + q * 4 + r2;
        const long col = n0 + wc + bi * 16 + m;
        xrow[row * DM + col] = acc[ai][bi][r2] + (float)hb[row * DM + col];
      }
}

// ---------------------------------------------------------------------------
// K5: LayerNorm rows of xrow -> out (validated rounds 4-8).
// ---------------------------------------------------------------------------
__global__ __launch_bounds__(256) void ln_out(const float* __restrict__ xrow,
                                              const __bf16* __restrict__ gamma,
                                              const __bf16* __restrict__ beta,
                                              const int* __restrict__ flag,
                                              void* __restrict__ out) {
  const int f32 = flag[0];
  const int r = blockIdx.x;
  const int tid = threadIdx.x;
  __shared__ float red[256];
  const float x0 = xrow[(long)r * DM + tid];
  const float x1 = xrow[(long)r * DM + tid + 256];

  red[tid] = x0 + x1; __syncthreads();
  for (int s = 128; s > 0; s >>= 1) { if (tid < s) red[tid] += red[tid + s]; __syncthreads(); }
  const float mu = red[0] * (1.f / 512.f); __syncthreads();
  red[tid] = x0 * x0 + x1 * x1; __syncthreads();
  for (int s = 128; s > 0; s >>= 1) { if (tid < s) red[tid] += red[tid + s]; __syncthreads(); }
  const float var = red[0] * (1.f / 512.f) - mu * mu; __syncthreads();
  const float rstd = rsqrtf(var + 1e-5f);

  stmix(out, (long)r * DM + tid,
        (x0 - mu) * rstd * (float)gamma[tid] + (float)beta[tid], f32);
  stmix(out, (long)r * DM + tid + 256,
        (x1 - mu) * rstd * (float)gamma[tid + 256] + (float)beta[tid + 256], f32);
}

// ---------------------------------------------------------------------------
extern "C" void kernel_launch(void* const* d_in, const int* in_sizes, int n_in,
                              void* d_out, int out_size, void* d_ws, size_t ws_size,
                              hipStream_t stream) {
  (void)in_sizes; (void)n_in; (void)out_size; (void)ws_size;
  char* ws = (char*)d_ws;
  __bf16* qkv   = (__bf16*)ws;
  int*    flag  = (int*)(ws + 33554432);
  __bf16* wt    = (__bf16*)(ws + 33554688);
  __bf16* wot   = (__bf16*)(ws + 35651840);
  __bf16* att   = (__bf16*)(ws + 36176128);
  __bf16* vt    = (__bf16*)(ws + 44564736);
  __bf16* hb    = (__bf16*)(ws + 52953344);
  __bf16* projT = (__bf16*)(ws + 61341952);
  __bf16* pi0b  = (__bf16*)(ws + 61374720);
  __bf16* pi1b  = (__bf16*)(ws + 61378816);
  __bf16* gamb  = (__bf16*)(ws + 61382912);
  __bf16* betb  = (__bf16*)(ws + 61383936);
  float*  xrow  = (float*)(ws + 61384960);   // 16 MB
  __bf16* projB = (__bf16*)(ws + 78163968);  // 32 KB fragment-native proj
  __bf16* kf    = (__bf16*)(ws + 128493824);

  prep<<<PREP_BLOCKS, 256, 0, stream>>>(d_in[0], d_in[1], d_in[2], d_in[7],
                                        d_in[5], d_in[6], d_in[3], d_in[4],
                                        flag, hb, wt, wot, projT,
                                        pi0b, pi1b, gamb, betb, projB);
  gemm_h_wqkv<<<dim3(16, 64), 256, 0, stream>>>(hb, wt, qkv);
  vpack<<<dim3(4, 256), 256, 0, stream>>>(qkv, vt);
  features_mfma<<<dim3(4, 256), 256, 0, stream>>>(qkv, projB, pi0b, pi1b, kf);
  flash_mfma<<<dim3(1024), 128, 0, stream>>>(qkv, projB, kf, vt, att);
  gemm_att_wo<<<dim3(4, 64), 256, 0, stream>>>(att, wot, hb, xrow);
  ln_out<<<dim3(ROWS), 256, 0, stream>>>(xrow, gamb, betb, flag, d_out);
}

// Round 7
// 216.569 us; speedup vs baseline: 1.3562x; 1.0155x over previous
//
#include <hip/hip_runtime.h>
#include <hip/hip_bf16.h>

// L=256, B=32, H=8, d_head=64, m=256, feature dim 2m=512, D_MODEL=512
#define L_SEQ 256
#define B_SZ  32
#define NH    8
#define DH    64
#define DM    512
#define FD    512
#define PM    256
#define ROWS  8192
#define QKVN  2048

typedef __bf16 bf16x8 __attribute__((ext_vector_type(8)));
typedef __bf16 bf16x4 __attribute__((ext_vector_type(4)));
typedef float f32x4 __attribute__((ext_vector_type(4)));
#define MFMA16(a, b, c) __builtin_amdgcn_mfma_f32_16x16x32_bf16((a), (b), (c), 0, 0, 0)

// ---------------------------------------------------------------------------
// P0: prep — probe + h-cvt + 3 transposes + tiny cvts + projB fragment pack.
// projB layout (fragment-native): chunk (c,kk) at lane=q*16+m, elem e holds
// projT[p = c*16+m][d = kk*32+q*8+e] = proj[d][p] = T[kk*32+q*8+e][p-n0].
// ---------------------------------------------------------------------------
#define PREP_HB   2048
#define PREP_WT   256
#define PREP_WOT  64
#define PREP_PJ   4
#define PREP_TINY 1
#define PREP_BLOCKS (PREP_HB + PREP_WT + PREP_WOT + PREP_PJ + PREP_TINY)

__global__ __launch_bounds__(256) void prep(
    const void* __restrict__ h, const void* __restrict__ wqkv,
    const void* __restrict__ wo, const void* __restrict__ proj,
    const void* __restrict__ pi0, const void* __restrict__ pi1,
    const void* __restrict__ gam, const void* __restrict__ bet,
    int* __restrict__ flag, __bf16* __restrict__ hb, __bf16* __restrict__ wt,
    __bf16* __restrict__ wot, __bf16* __restrict__ projT,
    __bf16* __restrict__ pi0b, __bf16* __restrict__ pi1b,
    __bf16* __restrict__ gamb, __bf16* __restrict__ betb,
    __bf16* __restrict__ projB) {
  __shared__ float T[64][69];
  __shared__ int red[256];
  const int tid = threadIdx.x;
  int cnt = 0;
  {
    const unsigned short* hbits = (const unsigned short*)h;
    for (int i = 0; i < 16; ++i) {
      const unsigned short u = hbits[tid * 16 + i];
      if (((u >> 7) & 0xFF) >= 0xA0) ++cnt;
    }
  }
  red[tid] = cnt; __syncthreads();
  for (int s = 128; s > 0; s >>= 1) { if (tid < s) red[tid] += red[tid + s]; __syncthreads(); }
  const int f32 = (red[0] >= 64) ? 1 : 0;
  __syncthreads();

  const int blk = blockIdx.x;
  if (blk < PREP_HB) {
    const int i = blk * 256 + tid;
    if (f32) {
      const f32x4* s = (const f32x4*)h;
      const f32x4 a = s[i * 2], b = s[i * 2 + 1];
      bf16x8 t;
      t[0] = (__bf16)a[0]; t[1] = (__bf16)a[1]; t[2] = (__bf16)a[2]; t[3] = (__bf16)a[3];
      t[4] = (__bf16)b[0]; t[5] = (__bf16)b[1]; t[6] = (__bf16)b[2]; t[7] = (__bf16)b[3];
      *reinterpret_cast<bf16x8*>(hb + (long)i * 8) = t;
    } else {
      *reinterpret_cast<bf16x8*>(hb + (long)i * 8) = ((const bf16x8*)h)[i];
    }
    return;
  }
  const void* src; __bf16* dst; int M, N, n0, m0;
  int pjx = -1;
  if (blk < PREP_HB + PREP_WT) {
    const int x = blk - PREP_HB;
    src = wqkv; dst = wt; M = 512; N = 2048; n0 = (x & 31) * 64; m0 = (x >> 5) * 64;
  } else if (blk < PREP_HB + PREP_WT + PREP_WOT) {
    const int x = blk - PREP_HB - PREP_WT;
    src = wo; dst = wot; M = 512; N = 512; n0 = (x & 7) * 64; m0 = (x >> 3) * 64;
  } else if (blk < PREP_HB + PREP_WT + PREP_WOT + PREP_PJ) {
    const int x = blk - PREP_HB - PREP_WT - PREP_WOT;
    src = proj; dst = projT; M = 64; N = 256; n0 = x * 64; m0 = 0;
    pjx = x;
  } else {
    if (tid == 0) flag[0] = f32;
    if (f32) {
      const float* s0 = (const float*)pi0; const float* s1 = (const float*)pi1;
      const float* s2 = (const float*)gam; const float* s3 = (const float*)bet;
      for (int i = tid; i < NH * 256; i += 256) { pi0b[i] = (__bf16)s0[i]; pi1b[i] = (__bf16)s1[i]; }
      for (int i = tid; i < DM; i += 256)      { gamb[i] = (__bf16)s2[i]; betb[i] = (__bf16)s3[i]; }
    } else {
      const __bf16* s0 = (const __bf16*)pi0; const __bf16* s1 = (const __bf16*)pi1;
      const __bf16* s2 = (const __bf16*)gam; const __bf16* s3 = (const __bf16*)bet;
      for (int i = tid; i < NH * 256; i += 256) { pi0b[i] = s0[i]; pi1b[i] = s1[i]; }
      for (int i = tid; i < DM; i += 256)      { gamb[i] = s2[i]; betb[i] = s3[i]; }
    }
    return;
  }
  if (f32) {
    const float* s = (const float*)src;
#pragma unroll
    for (int rep = 0; rep < 16; ++rep) {
      const int i = rep * 4 + (tid >> 6), j = tid & 63;
      T[i][j] = s[(long)(m0 + i) * N + n0 + j];
    }
  } else {
    const __bf16* s = (const __bf16*)src;
#pragma unroll
    for (int rep = 0; rep < 16; ++rep) {
      const int i = rep * 4 + (tid >> 6), j = tid & 63;
      T[i][j] = (float)s[(long)(m0 + i) * N + n0 + j];
    }
  }
  __syncthreads();
#pragma unroll
  for (int rep = 0; rep < 16; ++rep) {
    const int i = rep * 4 + (tid >> 6), j = tid & 63;
    dst[(long)(n0 + i) * M + m0 + j] = (__bf16)T[j][i];
  }
  if (pjx >= 0) {
    // fragment-native pack. T[d][p-n0] (rows = d, cols = feature):
    // chunk c=pjx*4+sub, lane (m,q), elem e := proj[d = kk*32+q*8+e][p = c*16+m]
    const int lane = tid & 63, sub = tid >> 6;
    const int mm = lane & 15, qq = lane >> 4;
#pragma unroll
    for (int kk2 = 0; kk2 < 2; ++kk2) {
      bf16x8 v;
#pragma unroll
      for (int e = 0; e < 8; ++e) v[e] = (__bf16)T[kk2 * 32 + qq * 8 + e][sub * 16 + mm];
      *reinterpret_cast<bf16x8*>(projB + ((pjx * 4 + sub) * 2 + kk2) * 512 + lane * 8) = v;
    }
  }
}

// ---------------------------------------------------------------------------
// K1: qkv = hb @ w_qkv, 128x128 tile, BK=64, per-wave 64x64 (validated r13).
// ---------------------------------------------------------------------------
__global__ __launch_bounds__(256) void gemm_h_wqkv(const __bf16* __restrict__ A,
                                                   const __bf16* __restrict__ Bt,
                                                   __bf16* __restrict__ C) {
  __shared__ __bf16 At[128][72];
  __shared__ __bf16 Bts[128][72];
  const int n0 = blockIdx.x * 128, m0 = blockIdx.y * 128;
  const int tid = threadIdx.x, lane = tid & 63, wv = tid >> 6;
  const int m = lane & 15, q = lane >> 4;
  const int wr = (wv >> 1) * 64, wc = (wv & 1) * 64;
  const int r = tid >> 1, c0 = (tid & 1) * 32;
  const __bf16* ap = A + (long)(m0 + r) * DM + c0;
  const __bf16* bp = Bt + (long)(n0 + r) * DM + c0;
  f32x4 acc[4][4];
#pragma unroll
  for (int i = 0; i < 4; ++i)
#pragma unroll
    for (int j = 0; j < 4; ++j) acc[i][j] = f32x4{0.f, 0.f, 0.f, 0.f};

  bf16x8 ar[4], br[4];
#pragma unroll
  for (int j = 0; j < 4; ++j) {
    ar[j] = *reinterpret_cast<const bf16x8*>(ap + j * 8);
    br[j] = *reinterpret_cast<const bf16x8*>(bp + j * 8);
  }
  for (int k0 = 0; k0 < DM; k0 += 64) {
    __syncthreads();
#pragma unroll
    for (int j = 0; j < 4; ++j) {
      *reinterpret_cast<bf16x8*>(&At[r][c0 + j * 8]) = ar[j];
      *reinterpret_cast<bf16x8*>(&Bts[r][c0 + j * 8]) = br[j];
    }
    if (k0 + 64 < DM) {
#pragma unroll
      for (int j = 0; j < 4; ++j) {
        ar[j] = *reinterpret_cast<const bf16x8*>(ap + k0 + 64 + j * 8);
        br[j] = *reinterpret_cast<const bf16x8*>(bp + k0 + 64 + j * 8);
      }
    }
    __syncthreads();
#pragma unroll
    for (int kk = 0; kk < 2; ++kk) {
      bf16x8 af[4], bfv[4];
#pragma unroll
      for (int i = 0; i < 4; ++i) {
        af[i]  = *reinterpret_cast<const bf16x8*>(&At[wr + i * 16 + m][kk * 32 + q * 8]);
        bfv[i] = *reinterpret_cast<const bf16x8*>(&Bts[wc + i * 16 + m][kk * 32 + q * 8]);
      }
#pragma unroll
      for (int ai = 0; ai < 4; ++ai)
#pragma unroll
        for (int bi = 0; bi < 4; ++bi)
          acc[ai][bi] = MFMA16(af[ai], bfv[bi], acc[ai][bi]);
    }
  }
#pragma unroll
  for (int ai = 0; ai < 4; ++ai)
#pragma unroll
    for (int r2 = 0; r2 < 4; ++r2)
#pragma unroll
      for (int bi = 0; bi < 4; ++bi)
        C[(long)(m0 + wr + ai * 16 + q * 4 + r2) * QKVN + n0 + wc + bi * 16 + m] =
            (__bf16)acc[ai][bi][r2];
}

// ---------------------------------------------------------------------------
// K2: kf-features + FUSED V-pack (round 15). Same grid as old vpack (4,256);
// reads the same qkv cache lines. V transpose LDS rides alongside As
// (27.6 KB total). V chunk store issued right after the barrier so the VMEM
// store overlaps the VALU-heavy softmax.
// ---------------------------------------------------------------------------
__global__ __launch_bounds__(256) void features_mfma(const __bf16* __restrict__ qkv,
                                                     const __bf16* __restrict__ projB,
                                                     const __bf16* __restrict__ pi0,
                                                     const __bf16* __restrict__ pi1,
                                                     __bf16* __restrict__ kf,
                                                     __bf16* __restrict__ vt) {
  const int st = blockIdx.x;
  const int l0 = st * 64;
  const int bh = blockIdx.y;
  const int h = bh & 7, b = bh >> 3;
  const int tid = threadIdx.x, lane = tid & 63, wv = tid >> 6;
  const int m = lane & 15, q = lane >> 4;
  __shared__ __bf16 As[2][64][72];   // k1 / k2 tiles: 64 l-rows x 64 d
  __shared__ __bf16 VT[64][72];      // V transpose [d][s]

  {
    const int r = tid >> 2, c0 = (tid & 3) * 16;
    const __bf16* ap = qkv + (long)((l0 + r) * B_SZ + b) * QKVN + h * 256 + 64 + c0;
#pragma unroll
    for (int t2 = 0; t2 < 2; ++t2) {
      *reinterpret_cast<bf16x8*>(&As[t2][r][c0]) =
          *reinterpret_cast<const bf16x8*>(ap + t2 * 64);
      *reinterpret_cast<bf16x8*>(&As[t2][r][c0 + 8]) =
          *reinterpret_cast<const bf16x8*>(ap + t2 * 64 + 8);
    }
    // V slice -> transpose into VT
    const __bf16* vp = ap + 128;       // offset 192 = 64 + 128
#pragma unroll
    for (int j = 0; j < 16; ++j) VT[c0 + j][r] = vp[j];
  }
  const int l = l0 + wv * 16 + m;          // this thread's sequence row
  const float p0w = (float)pi0[h * 256 + l];
  const float p1w = (float)pi1[h * 256 + l];
  const float SQ = 0.35355339f;            // 64^-0.25
  const float SK2 = 0.24748737f;           // 0.7 * 64^-0.25
  __syncthreads();

  // V-pack store (fragment-native chunks), overlaps following VALU work
  {
    const int c2 = tid >> 6;
    const int d = c2 * 16 + m;
#pragma unroll
    for (int kk = 0; kk < 2; ++kk) {
      const bf16x8 v = *reinterpret_cast<const bf16x8*>(&VT[d][kk * 32 + q * 8]);
      *reinterpret_cast<bf16x8*>(vt + (((long)bh * 8 + st * 2 + kk) * 4 + c2) * 512 + lane * 8) = v;
    }
  }

  f32x4 acc1[16], acc2[16];
#pragma unroll
  for (int c = 0; c < 16; ++c) {
    acc1[c] = f32x4{0.f, 0.f, 0.f, 0.f};
    acc2[c] = f32x4{0.f, 0.f, 0.f, 0.f};
  }
#pragma unroll
  for (int kk = 0; kk < 2; ++kk) {
    const bf16x8 x1 = *reinterpret_cast<const bf16x8*>(&As[0][wv * 16 + m][kk * 32 + q * 8]);
    const bf16x8 x2 = *reinterpret_cast<const bf16x8*>(&As[1][wv * 16 + m][kk * 32 + q * 8]);
#pragma unroll
    for (int c = 0; c < 16; ++c) {
      const bf16x8 wf =
          *reinterpret_cast<const bf16x8*>(projB + (c * 2 + kk) * 512 + lane * 8);
      acc1[c] = MFMA16(wf, x1, acc1[c]);   // acc[c][r] = [l=wv*16+m][p=c*16+q*4+r]
      acc2[c] = MFMA16(wf, x2, acc2[c]);
    }
  }
  float mx1 = 0.f, mx2 = 0.f;
#pragma unroll
  for (int c = 0; c < 16; ++c)
#pragma unroll
    for (int r = 0; r < 4; ++r) {
      mx1 = fmaxf(mx1, fabsf(acc1[c][r] * SQ));
      mx2 = fmaxf(mx2, fabsf(acc2[c][r] * SK2));
    }
  mx1 = fmaxf(mx1, __shfl_xor(mx1, 16)); mx1 = fmaxf(mx1, __shfl_xor(mx1, 32));
  mx2 = fmaxf(mx2, __shfl_xor(mx2, 16)); mx2 = fmaxf(mx2, __shfl_xor(mx2, 32));
  const float C21 = __expf(-2.f * mx1);
  const float C22 = __expf(-2.f * mx2);
  float sm1 = 0.f, sm2 = 0.f;
#pragma unroll
  for (int c = 0; c < 16; ++c)
#pragma unroll
    for (int r = 0; r < 4; ++r) {
      const float e11 = __expf(acc1[c][r] * SQ - mx1);
      const float e12 = __expf(acc2[c][r] * SK2 - mx2);
      sm1 += e11 + C21 * __builtin_amdgcn_rcpf(e11);
      sm2 += e12 + C22 * __builtin_amdgcn_rcpf(e12);
      acc1[c][r] = e11;
      acc2[c][r] = e12;
    }
  sm1 += __shfl_xor(sm1, 16); sm1 += __shfl_xor(sm1, 32);
  sm2 += __shfl_xor(sm2, 16); sm2 += __shfl_xor(sm2, 32);
  const float w1 = p0w * __builtin_amdgcn_rcpf(sm1);
  const float w2 = p1w * __builtin_amdgcn_rcpf(sm2);
  const float K1 = C21 * w1, K2 = C22 * w2;
  // fragment-native store: chunk [lt = l>>4][c], lane offset = lane*8
  __bf16* op = kf + (((long)bh * 16 + (l >> 4)) * 16) * 512 + lane * 8;
#pragma unroll
  for (int c = 0; c < 16; ++c) {
    bf16x8 v;
#pragma unroll
    for (int r = 0; r < 4; ++r) {
      v[r]     = (__bf16)(w1 * acc1[c][r] + w2 * acc2[c][r]);
      v[4 + r] = (__bf16)(K1 * __builtin_amdgcn_rcpf(acc1[c][r]) +
                          K2 * __builtin_amdgcn_rcpf(acc2[c][r]));
    }
    *reinterpret_cast<bf16x8*>(op + c * 512) = v;
  }
}

// ---------------------------------------------------------------------------
// K3: flash (validated round 12/13, REVERTED from the round-14 2-frag variant
// which spilled: VGPR cap 124 < 128 needed for qT0+qT1). Barrier-free,
// fragment-native coalesced loads, wave-private Pt, id%8==bh%8 XCD locality.
// ---------------------------------------------------------------------------
__global__ __launch_bounds__(256, 3) void flash_mfma(const __bf16* __restrict__ qkv,
                                                     const __bf16* __restrict__ projB,
                                                     const __bf16* __restrict__ kf,
                                                     const __bf16* __restrict__ vt,
                                                     __bf16* __restrict__ att) {
  const int id = blockIdx.x;
  const int bh = id & 255;
  const int t  = ((id >> 8) + id) & 3;   // bijective per bh, mixed per round
  const int h = bh & 7, b = bh >> 3;
  const int tid = threadIdx.x, lane = tid & 63, wv = tid >> 6;
  const int m = lane & 15, q = lane >> 4;
  __shared__ __bf16 Pt[64][72];          // wave-private rows

  // ---------------- feature phase: qT[16] in-register ----------------
  const float SQ = 0.35355339f;          // 64^-0.25
  f32x4 acc[16];
#pragma unroll
  for (int c = 0; c < 16; ++c) acc[c] = f32x4{0.f, 0.f, 0.f, 0.f};
  const __bf16* xb = qkv + (long)((t * 64 + wv * 16 + m) * B_SZ + b) * QKVN + h * 256;
#pragma unroll
  for (int kk = 0; kk < 2; ++kk) {
    const bf16x8 xf = *reinterpret_cast<const bf16x8*>(xb + kk * 32 + q * 8);
#pragma unroll
    for (int c = 0; c < 16; ++c) {
      const bf16x8 wf =
          *reinterpret_cast<const bf16x8*>(projB + (c * 2 + kk) * 512 + lane * 8);
      acc[c] = MFMA16(wf, xf, acc[c]);   // acc[c][r] = qf-pre[l=wv*16+m][p=c*16+q*4+r]
    }
  }
  float mx = 0.f;
#pragma unroll
  for (int c = 0; c < 16; ++c)
#pragma unroll
    for (int r = 0; r < 4; ++r) mx = fmaxf(mx, fabsf(acc[c][r] * SQ));
  mx = fmaxf(mx, __shfl_xor(mx, 16));
  mx = fmaxf(mx, __shfl_xor(mx, 32));
  const float C2 = __expf(-2.f * mx);
  float sm = 0.f;
#pragma unroll
  for (int c = 0; c < 16; ++c)
#pragma unroll
    for (int r = 0; r < 4; ++r) {
      const float e1 = __expf(acc[c][r] * SQ - mx);
      sm += e1 + C2 * __builtin_amdgcn_rcpf(e1);
      acc[c][r] = e1;
    }
  sm += __shfl_xor(sm, 16);
  sm += __shfl_xor(sm, 32);
  const float inv = __builtin_amdgcn_rcpf(sm);
  const float K2 = C2 * inv;
  bf16x8 qT[16];                         // A-frags, k = q*8 + (r + 4*neg)
#pragma unroll
  for (int c = 0; c < 16; ++c) {
    bf16x8 v;
#pragma unroll
    for (int r = 0; r < 4; ++r) {
      v[r]     = (__bf16)(acc[c][r] * inv);
      v[4 + r] = (__bf16)(K2 * __builtin_amdgcn_rcpf(acc[c][r]));
    }
    qT[c] = v;
  }

  // ---------------- main loop: barrier-free, coalesced fragments ----------------
  f32x4 o[4];
#pragma unroll
  for (int i = 0; i < 4; ++i) o[i] = f32x4{0.f, 0.f, 0.f, 0.f};
  float den[4] = {0.f, 0.f, 0.f, 0.f};

  const __bf16* kfb = kf + (long)bh * (16 * 16 * 512) + lane * 8;
  const __bf16* vtb = vt + (long)bh * (8 * 4 * 512) + lane * 8;

  for (int st = 0; st <= t; ++st) {
    f32x4 s[4];
#pragma unroll
    for (int i = 0; i < 4; ++i) s[i] = f32x4{0.f, 0.f, 0.f, 0.f};
#pragma unroll
    for (int g = 0; g < 16; ++g) {
      const __bf16* kp = kfb + ((long)(st * 4) * 16 + g) * 512;
      const bf16x8 kb0 = *reinterpret_cast<const bf16x8*>(kp);
      const bf16x8 kb1 = *reinterpret_cast<const bf16x8*>(kp + 16 * 512);
      const bf16x8 kb2 = *reinterpret_cast<const bf16x8*>(kp + 32 * 512);
      const bf16x8 kb3 = *reinterpret_cast<const bf16x8*>(kp + 48 * 512);
      s[0] = MFMA16(qT[g], kb0, s[0]);
      s[1] = MFMA16(qT[g], kb1, s[1]);
      s[2] = MFMA16(qT[g], kb2, s[2]);
      s[3] = MFMA16(qT[g], kb3, s[3]);
    }
    // V fragments for this step (coalesced 1KB chunks)
    bf16x8 vf[8];
#pragma unroll
    for (int kk = 0; kk < 2; ++kk)
#pragma unroll
      for (int c = 0; c < 4; ++c)
        vf[kk * 4 + c] =
            *reinterpret_cast<const bf16x8*>(vtb + (((long)st * 2 + kk) * 4 + c) * 512);
    const bool last = (st == t);
#pragma unroll
    for (int c = 0; c < 4; ++c)
#pragma unroll
      for (int r = 0; r < 4; ++r) {
        const int row = wv * 16 + q * 4 + r, col = c * 16 + m;
        const float v = (last && col > row) ? 0.f : s[c][r];
        den[r] += v;
        Pt[row][col] = (__bf16)v;
      }
#pragma unroll
    for (int kk = 0; kk < 2; ++kk) {
      const bf16x8 pf = *reinterpret_cast<const bf16x8*>(&Pt[wv * 16 + m][kk * 32 + q * 8]);
#pragma unroll
      for (int c = 0; c < 4; ++c)
        o[c] = MFMA16(pf, vf[kk * 4 + c], o[c]);
    }
  }
#pragma unroll
  for (int r = 0; r < 4; ++r) {
    float d = den[r];
    d += __shfl_xor(d, 1); d += __shfl_xor(d, 2);
    d += __shfl_xor(d, 4); d += __shfl_xor(d, 8);
    const float invd = 0.125f / (d + 1e-5f);           // SCALE=64^-0.5, EPS
    const int row = t * 64 + wv * 16 + q * 4 + r;
#pragma unroll
    for (int c = 0; c < 4; ++c)
      att[((long)(row * B_SZ + b)) * DM + h * DH + c * 16 + m] = (__bf16)(o[c][r] * invd);
  }
}

// ---------------------------------------------------------------------------
// K4: xrow = hb + att @ w_o (f32 out), 128x128 tile (validated r13).
// ---------------------------------------------------------------------------
__global__ __launch_bounds__(256) void gemm_att_wo(const __bf16* __restrict__ A,
                                                   const __bf16* __restrict__ Bt,
                                                   const __bf16* __restrict__ hb,
                                                   float* __restrict__ xrow) {
  __shared__ __bf16 At[128][72];
  __shared__ __bf16 Bts[128][72];
  const int n0 = blockIdx.x * 128, m0 = blockIdx.y * 128;
  const int tid = threadIdx.x, lane = tid & 63, wv = tid >> 6;
  const int m = lane & 15, q = lane >> 4;
  const int wr = (wv >> 1) * 64, wc = (wv & 1) * 64;
  const int r = tid >> 1, c0 = (tid & 1) * 32;
  const __bf16* ap = A + (long)(m0 + r) * DM + c0;
  const __bf16* bp = Bt + (long)(n0 + r) * DM + c0;
  f32x4 acc[4][4];
#pragma unroll
  for (int i = 0; i < 4; ++i)
#pragma unroll
    for (int j = 0; j < 4; ++j) acc[i][j] = f32x4{0.f, 0.f, 0.f, 0.f};

  bf16x8 ar[4], br[4];
#pragma unroll
  for (int j = 0; j < 4; ++j) {
    ar[j] = *reinterpret_cast<const bf16x8*>(ap + j * 8);
    br[j] = *reinterpret_cast<const bf16x8*>(bp + j * 8);
  }
  for (int k0 = 0; k0 < DM; k0 += 64) {
    __syncthreads();
#pragma unroll
    for (int j = 0; j < 4; ++j) {
      *reinterpret_cast<bf16x8*>(&At[r][c0 + j * 8]) = ar[j];
      *reinterpret_cast<bf16x8*>(&Bts[r][c0 + j * 8]) = br[j];
    }
    if (k0 + 64 < DM) {
#pragma unroll
      for (int j = 0; j < 4; ++j) {
        ar[j] = *reinterpret_cast<const bf16x8*>(ap + k0 + 64 + j * 8);
        br[j] = *reinterpret_cast<const bf16x8*>(bp + k0 + 64 + j * 8);
      }
    }
    __syncthreads();
#pragma unroll
    for (int kk = 0; kk < 2; ++kk) {
      bf16x8 af[4], bfv[4];
#pragma unroll
      for (int i = 0; i < 4; ++i) {
        af[i]  = *reinterpret_cast<const bf16x8*>(&At[wr + i * 16 + m][kk * 32 + q * 8]);
        bfv[i] = *reinterpret_cast<const bf16x8*>(&Bts[wc + i * 16 + m][kk * 32 + q * 8]);
      }
#pragma unroll
      for (int ai = 0; ai < 4; ++ai)
#pragma unroll
        for (int bi = 0; bi < 4; ++bi)
          acc[ai][bi] = MFMA16(af[ai], bfv[bi], acc[ai][bi]);
    }
  }
#pragma unroll
  for (int ai = 0; ai < 4; ++ai)
#pragma unroll
    for (int r2 = 0; r2 < 4; ++r2)
#pragma unroll
      for (int bi = 0; bi < 4; ++bi) {
        const long row = m0 + wr + ai * 16 + q * 4 + r2;
        const long col = n0 + wc + bi * 16 + m;
        xrow[row * DM + col] = acc[ai][bi][r2] + (float)hb[row * DM + col];
      }
}

// ---------------------------------------------------------------------------
// K5: LayerNorm, round 15: wave-per-row, barrier-free shuffle reduction.
// Lane holds 8 f32 (two f32x4). grid = ROWS/4, 4 waves/block.
// ---------------------------------------------------------------------------
__global__ __launch_bounds__(256) void ln_out(const float* __restrict__ xrow,
                                              const __bf16* __restrict__ gamma,
                                              const __bf16* __restrict__ beta,
                                              const int* __restrict__ flag,
                                              void* __restrict__ out) {
  const int f32 = flag[0];
  const int tid = threadIdx.x, lane = tid & 63, wv = tid >> 6;
  const long r = (long)blockIdx.x * 4 + wv;
  const int c0 = lane * 4, c1 = 256 + lane * 4;
  const f32x4 x0 = *reinterpret_cast<const f32x4*>(xrow + r * DM + c0);
  const f32x4 x1 = *reinterpret_cast<const f32x4*>(xrow + r * DM + c1);

  float s = 0.f, s2 = 0.f;
#pragma unroll
  for (int i = 0; i < 4; ++i) {
    s += x0[i] + x1[i];
    s2 += x0[i] * x0[i] + x1[i] * x1[i];
  }
#pragma unroll
  for (int msk = 1; msk < 64; msk <<= 1) {
    s += __shfl_xor(s, msk);
    s2 += __shfl_xor(s2, msk);
  }
  const float mu = s * (1.f / 512.f);
  const float var = s2 * (1.f / 512.f) - mu * mu;
  const float rstd = rsqrtf(var + 1e-5f);

  if (f32) {
    f32x4 o0, o1;
#pragma unroll
    for (int i = 0; i < 4; ++i) {
      o0[i] = (x0[i] - mu) * rstd * (float)gamma[c0 + i] + (float)beta[c0 + i];
      o1[i] = (x1[i] - mu) * rstd * (float)gamma[c1 + i] + (float)beta[c1 + i];
    }
    *reinterpret_cast<f32x4*>((float*)out + r * DM + c0) = o0;
    *reinterpret_cast<f32x4*>((float*)out + r * DM + c1) = o1;
  } else {
    bf16x4 o0, o1;
#pragma unroll
    for (int i = 0; i < 4; ++i) {
      o0[i] = (__bf16)((x0[i] - mu) * rstd * (float)gamma[c0 + i] + (float)beta[c0 + i]);
      o1[i] = (__bf16)((x1[i] - mu) * rstd * (float)gamma[c1 + i] + (float)beta[c1 + i]);
    }
    *reinterpret_cast<bf16x4*>((__bf16*)out + r * DM + c0) = o0;
    *reinterpret_cast<bf16x4*>((__bf16*)out + r * DM + c1) = o1;
  }
}

// ---------------------------------------------------------------------------
extern "C" void kernel_launch(void* const* d_in, const int* in_sizes, int n_in,
                              void* d_out, int out_size, void* d_ws, size_t ws_size,
                              hipStream_t stream) {
  (void)in_sizes; (void)n_in; (void)out_size; (void)ws_size;
  char* ws = (char*)d_ws;
  __bf16* qkv   = (__bf16*)ws;
  int*    flag  = (int*)(ws + 33554432);
  __bf16* wt    = (__bf16*)(ws + 33554688);
  __bf16* wot   = (__bf16*)(ws + 35651840);
  __bf16* att   = (__bf16*)(ws + 36176128);
  __bf16* vt    = (__bf16*)(ws + 44564736);
  __bf16* hb    = (__bf16*)(ws + 52953344);
  __bf16* projT = (__bf16*)(ws + 61341952);
  __bf16* pi0b  = (__bf16*)(ws + 61374720);
  __bf16* pi1b  = (__bf16*)(ws + 61378816);
  __bf16* gamb  = (__bf16*)(ws + 61382912);
  __bf16* betb  = (__bf16*)(ws + 61383936);
  float*  xrow  = (float*)(ws + 61384960);   // 16 MB
  __bf16* projB = (__bf16*)(ws + 78163968);  // 32 KB fragment-native proj
  __bf16* kf    = (__bf16*)(ws + 128493824);

  prep<<<PREP_BLOCKS, 256, 0, stream>>>(d_in[0], d_in[1], d_in[2], d_in[7],
                                        d_in[5], d_in[6], d_in[3], d_in[4],
                                        flag, hb, wt, wot, projT,
                                        pi0b, pi1b, gamb, betb, projB);
  gemm_h_wqkv<<<dim3(16, 64), 256, 0, stream>>>(hb, wt, qkv);
  features_mfma<<<dim3(4, 256), 256, 0, stream>>>(qkv, projB, pi0b, pi1b, kf, vt);
  flash_mfma<<<dim3(1024), 256, 0, stream>>>(qkv, projB, kf, vt, att);
  gemm_att_wo<<<dim3(4, 64), 256, 0, stream>>>(att, wot, hb, xrow);
  ln_out<<<dim3(ROWS / 4), 256, 0, stream>>>(xrow, gamb, betb, flag, d_out);
}